// Round 13
// baseline (312.905 us; speedup 1.0000x reference)
//
#include <hip/hip_runtime.h>
#include <hip/hip_bf16.h>
#include <math.h>

#define TLEN 1024
#define HDIM 2048
#define NHEAD 32
#define HSZ 64
#define THE (TLEN * HDIM)
#define NC 32          // scan chunks
#define CT (TLEN / NC) // 32 timesteps per chunk

typedef __attribute__((ext_vector_type(8))) short bf16x8;
typedef __attribute__((ext_vector_type(4))) float f32x4;

__device__ __forceinline__ float waveRedSum(float v) {
#pragma unroll
  for (int off = 32; off > 0; off >>= 1) v += __shfl_xor(v, off, 64);
  return v;
}

__device__ __forceinline__ float bf2f(unsigned short u) {
  return __builtin_bit_cast(float, (unsigned)u << 16);
}

__device__ __forceinline__ void gll16(const __hip_bfloat16* g, __hip_bfloat16* l) {
  __builtin_amdgcn_global_load_lds(
      (const __attribute__((address_space(1))) void*)g,
      (__attribute__((address_space(3))) void*)l, 16, 0, 0);
}

// ---------- weight convert + transpose: src f32 [R][C] -> dst bf16 [C][R] ----------
struct TrArgs {
  const float* src[8];
  __hip_bfloat16* dst[8];
  int R[8];
  int C[8];
};

__global__ __launch_bounds__(256) void transp_kernel(TrArgs ta) {
  const int z = blockIdx.z;
  const int R = ta.R[z], C = ta.C[z];
  const int c0 = blockIdx.x * 32, r0 = blockIdx.y * 32;
  if (c0 >= C || r0 >= R) return;
  __shared__ float tile[32][33];
  const int tx = threadIdx.x & 31, ty = threadIdx.x >> 5;
  const float* src = ta.src[z];
  __hip_bfloat16* dst = ta.dst[z];
#pragma unroll
  for (int i = 0; i < 4; i++)
    tile[ty + i * 8][tx] = src[(size_t)(r0 + ty + i * 8) * C + c0 + tx];
  __syncthreads();
#pragma unroll
  for (int i = 0; i < 4; i++)
    dst[(size_t)(c0 + ty + i * 8) * R + r0 + tx] = __float2bfloat16(tile[tx][ty + i * 8]);
}

// ---------- LayerNorm (rows t and t-1) + token-shift fused ----------
// Computes xl[t] = LN(x[t]); xxx[t] = xl[t] + (past - xl[t])*tmx where
// past = LN(x[t-1]) (recomputed redundantly) or s1 raw at t=0.
__global__ __launch_bounds__(256) void ln1_kernel(const float* __restrict__ x,
                                                  const float* __restrict__ w,
                                                  const float* __restrict__ b,
                                                  const float* __restrict__ s1,
                                                  const float* __restrict__ tmx,
                                                  float* __restrict__ xl,
                                                  __hip_bfloat16* __restrict__ xxx,
                                                  float* __restrict__ s1out) {
  const int t = blockIdx.x;
  const int tid = threadIdx.x;
  const int wid = tid >> 6, lane = tid & 63;
  const float4* xr = (const float4*)(x + (size_t)t * HDIM);
  const float4* xp = (const float4*)(x + (size_t)(t > 0 ? t - 1 : 0) * HDIM);
  float4 a = xr[tid], c = xr[tid + 256];
  float4 ap = xp[tid], cp = xp[tid + 256];
  float va[8] = {a.x, a.y, a.z, a.w, c.x, c.y, c.z, c.w};
  float vp[8] = {ap.x, ap.y, ap.z, ap.w, cp.x, cp.y, cp.z, cp.w};
  float sum = 0.f, sump = 0.f;
#pragma unroll
  for (int i = 0; i < 8; i++) { sum += va[i]; sump += vp[i]; }
  sum = waveRedSum(sum);
  sump = waveRedSum(sump);
  __shared__ float red[16];
  if (lane == 0) { red[wid] = sum; red[8 + wid] = sump; }
  __syncthreads();
  const float mu = (red[0] + red[1] + red[2] + red[3]) * (1.f / HDIM);
  const float mup = (red[8] + red[9] + red[10] + red[11]) * (1.f / HDIM);
  float vs = 0.f, vsp = 0.f;
#pragma unroll
  for (int i = 0; i < 8; i++) {
    float d = va[i] - mu; vs += d * d;
    float dp = vp[i] - mup; vsp += dp * dp;
  }
  vs = waveRedSum(vs);
  vsp = waveRedSum(vsp);
  if (lane == 0) { red[4 + wid] = vs; red[12 + wid] = vsp; }
  __syncthreads();
  const float rstd = rsqrtf((red[4] + red[5] + red[6] + red[7]) * (1.f / HDIM) + 1e-5f);
  const float rstdp = rsqrtf((red[12] + red[13] + red[14] + red[15]) * (1.f / HDIM) + 1e-5f);
  float* xrow = xl + (size_t)t * HDIM;
  __hip_bfloat16* xxrow = xxx + (size_t)t * HDIM;
#pragma unroll
  for (int i = 0; i < 8; i++) {
    const int idx = (i < 4) ? (4 * tid + i) : (1024 + 4 * tid + (i - 4));
    const float wv = w[idx], bv = b[idx];
    const float cur = (va[i] - mu) * rstd * wv + bv;
    const float past = (t > 0) ? (vp[i] - mup) * rstdp * wv + bv : s1[idx];
    xrow[idx] = cur;
    xxrow[idx] = __float2bfloat16(cur + (past - cur) * tmx[idx]);
    if (t == TLEN - 1) s1out[idx] = cur;
  }
}

// ---------- mix: x5[f] = xl + sx * (t5[f] @ w2[f] + time_maa[f]) ----------
__global__ __launch_bounds__(256) void mix_kernel(const float* __restrict__ t5,
                                                  const float* __restrict__ xl,
                                                  const float* __restrict__ s1,
                                                  const float* __restrict__ w2,
                                                  const float* __restrict__ maa,
                                                  __hip_bfloat16* __restrict__ x5b) {
  const int h = blockIdx.x * 256 + threadIdx.x;
  const int t0 = blockIdx.y * 8;
  __shared__ float t5L[8 * 160];
  for (int i = threadIdx.x; i < 8 * 160; i += 256) {
    const int rr = i / 160, cc = i - rr * 160;
    t5L[i] = t5[(size_t)(t0 + rr) * 160 + cc];
  }
  __syncthreads();
  float mixv[8][5];
#pragma unroll
  for (int ts = 0; ts < 8; ts++)
#pragma unroll
    for (int f = 0; f < 5; f++) mixv[ts][f] = 0.f;
#pragma unroll
  for (int f = 0; f < 5; f++) {
#pragma unroll 4
    for (int m = 0; m < 32; m++) {
      const float w2v = w2[(size_t)(f * 32 + m) * HDIM + h];
#pragma unroll
      for (int ts = 0; ts < 8; ts++) mixv[ts][f] += t5L[ts * 160 + f * 32 + m] * w2v;
    }
  }
#pragma unroll
  for (int ts = 0; ts < 8; ts++) {
    const int t = t0 + ts;
    const float cur = xl[(size_t)t * HDIM + h];
    const float past = (t > 0) ? xl[(size_t)(t - 1) * HDIM + h] : s1[h];
    const float sx = past - cur;
#pragma unroll
    for (int f = 0; f < 5; f++) {
      const float v = cur + sx * (mixv[ts][f] + maa[(size_t)f * HDIM + h]);
      x5b[(size_t)f * THE + (size_t)t * HDIM + h] = __float2bfloat16(v);
    }
  }
}

// ---------- batched MFMA GEMM: C[z] = epi( A[z](MxK) @ Bt[z](NxK)^T ) ----------
// BK=64, double-buffered LDS, counted-vmcnt pipeline, conflict-free swizzle.
struct GemmArgs {
  const __hip_bfloat16* A[8];
  const __hip_bfloat16* B[8];
  void* C[8];
  const float* aux[8];
  int epi[8];
  int M, N, K, Ks;
};

__global__ __launch_bounds__(256) void gemm_bt(GemmArgs ga) {
  const int z = blockIdx.z;
  const __hip_bfloat16* __restrict__ A = ga.A[z];
  const __hip_bfloat16* __restrict__ Bt = ga.B[z];
  const int N = ga.N, K = ga.K, Ks = ga.Ks;
  const int epi = ga.epi[z];
  const float* __restrict__ aux = ga.aux[z];
  void* Cz = ga.C[z];

  __shared__ __align__(16) __hip_bfloat16 As[2][128 * 64];
  __shared__ __align__(16) __hip_bfloat16 Bs[2][128 * 64];

  const int tid = threadIdx.x;
  const int wid = tid >> 6;
  const int lane = tid & 63;

  int bx = blockIdx.x, by = blockIdx.y;
  if (gridDim.x == 8 && gridDim.y == 16) {
    const int flat = bx + 8 * by;
    const int xcd = flat & 7, rem = flat >> 3;
    bx = rem & 7;
    by = xcd + 8 * (rem >> 3);
  }
  const int m0 = bx * 128;
  const int n0 = by * 128;
  const int wr = wid >> 1, wc = wid & 1;

  const int srow = lane >> 3;
  const int chunkS = (lane & 7) ^ srow;
  const __hip_bfloat16* aSrcQ[4];
  const __hip_bfloat16* bSrcQ[4];
#pragma unroll
  for (int q = 0; q < 4; q++) {
    const int arow = wid * 32 + q * 8 + srow;
    int brow = n0 + arow; if (brow > N - 1) brow = N - 1;
    aSrcQ[q] = A + (size_t)(m0 + arow) * Ks + chunkS * 8;
    bSrcQ[q] = Bt + (size_t)brow * Ks + chunkS * 8;
  }

  f32x4 acc[4][4];
#pragma unroll
  for (int m = 0; m < 4; m++)
#pragma unroll
    for (int n = 0; n < 4; n++) acc[m][n] = 0.f;

  const int lr = lane & 15;
  const int cbase = lane >> 4;
  int aoffk[2], boffk[2];
#pragma unroll
  for (int kg = 0; kg < 2; kg++) {
    const int phys = (kg * 4 + cbase) ^ (lr & 7);
    aoffk[kg] = (wr * 64 + lr) * 64 + phys * 8;
    boffk[kg] = (wc * 64 + lr) * 64 + phys * 8;
  }

#define STAGE(BUF, KT)                                              \
  do {                                                              \
    _Pragma("unroll") for (int q = 0; q < 4; q++) {                 \
      gll16(aSrcQ[q] + (KT), &As[BUF][(wid * 32 + q * 8) * 64]);    \
      gll16(bSrcQ[q] + (KT), &Bs[BUF][(wid * 32 + q * 8) * 64]);    \
    }                                                               \
  } while (0)

  STAGE(0, 0);
  int cur = 0;
  for (int kt = 0; kt < K; kt += 64) {
    const bool more = (kt + 64 < K);
    if (more) {
      STAGE(cur ^ 1, kt + 64);
      asm volatile("s_waitcnt vmcnt(8)" ::: "memory");
    } else {
      asm volatile("s_waitcnt vmcnt(0)" ::: "memory");
    }
    __builtin_amdgcn_s_barrier();
#pragma unroll
    for (int kg = 0; kg < 2; kg++) {
      bf16x8 af[4], bfv[4];
#pragma unroll
      for (int m = 0; m < 4; m++) af[m] = *(const bf16x8*)&As[cur][aoffk[kg] + m * 16 * 64];
#pragma unroll
      for (int n = 0; n < 4; n++) bfv[n] = *(const bf16x8*)&Bs[cur][boffk[kg] + n * 16 * 64];
#pragma unroll
      for (int m = 0; m < 4; m++)
#pragma unroll
        for (int n = 0; n < 4; n++)
          acc[m][n] = __builtin_amdgcn_mfma_f32_16x16x32_bf16(af[m], bfv[n], acc[m][n], 0, 0, 0);
    }
    __builtin_amdgcn_s_barrier();
    cur ^= 1;
  }
#undef STAGE

  const int r4 = (lane >> 4) * 4;
#pragma unroll
  for (int m = 0; m < 4; m++) {
#pragma unroll
    for (int n = 0; n < 4; n++) {
      const int gn = n0 + wc * 64 + n * 16 + lr;
      if (gn < N) {
#pragma unroll
        for (int r = 0; r < 4; r++) {
          const int gm = m0 + wr * 64 + m * 16 + r4 + r;
          const size_t idx = (size_t)gm * N + gn;
          const float v = acc[m][n][r];
          switch (epi) {
            case 0: ((__hip_bfloat16*)Cz)[idx] = __float2bfloat16(v); break;
            case 1: ((__hip_bfloat16*)Cz)[idx] = __float2bfloat16(v / (1.f + expf(-v))); break;
            case 2: ((float*)Cz)[idx] = tanhf(v); break;
            case 3: ((__hip_bfloat16*)Cz)[idx] = __float2bfloat16(tanhf(v)); break;
            case 5: ((float*)Cz)[idx] = v + aux[idx]; break;
            case 6: ((float*)Cz)[idx] = v; break;
          }
        }
      }
    }
  }
}

// ---------- split-K combines ----------
__global__ __launch_bounds__(256) void comb8_tanh_f32(const float* __restrict__ p,
                                                      float* __restrict__ o, int n) {
  const int i = blockIdx.x * 256 + threadIdx.x;
  float s = 0.f;
#pragma unroll
  for (int k = 0; k < 8; k++) s += p[(size_t)k * n + i];
  o[i] = tanhf(s);
}

__global__ __launch_bounds__(256) void comb8_tanh_bf16(const float* __restrict__ p,
                                                       __hip_bfloat16* __restrict__ o, int n) {
  const int i = blockIdx.x * 256 + threadIdx.x;
  float s = 0.f;
#pragma unroll
  for (int k = 0; k < 8; k++) s += p[(size_t)k * n + i];
  o[i] = __float2bfloat16(tanhf(s));
}

__global__ __launch_bounds__(256) void comb4_resid(const float* __restrict__ p,
                                                   const float* __restrict__ x,
                                                   float* __restrict__ o) {
  const int i = blockIdx.x * 256 + threadIdx.x;
  const float4 a = ((const float4*)p)[i];
  const float4 b = ((const float4*)(p + THE))[i];
  const float4 c = ((const float4*)(p + 2 * (size_t)THE))[i];
  const float4 d = ((const float4*)(p + 3 * (size_t)THE))[i];
  const float4 e = ((const float4*)x)[i];
  ((float4*)o)[i] = make_float4(a.x + b.x + c.x + d.x + e.x,
                                a.y + b.y + c.y + d.y + e.y,
                                a.z + b.z + c.z + d.z + e.z,
                                a.w + b.w + c.w + d.w + e.w);
}

// ---------- td = exp(-exp(clip(tw @ dw2 + dp)))  -- K=64 dot, memory-bound ----------
__global__ __launch_bounds__(256) void tdcalc_kernel(const __hip_bfloat16* __restrict__ tw,
                                                     const __hip_bfloat16* __restrict__ dw2t,
                                                     const float* __restrict__ dp,
                                                     float* __restrict__ td) {
  const int t0 = blockIdx.x * 4;
  const int n = blockIdx.y * 256 + threadIdx.x;
  __shared__ float twL[4][64];
  {
    const int row = threadIdx.x >> 6, col = threadIdx.x & 63;
    twL[row][col] = __bfloat162float(tw[(size_t)(t0 + row) * 64 + col]);
  }
  __syncthreads();
  float acc[4] = {0.f, 0.f, 0.f, 0.f};
  const bf16x8* drow = (const bf16x8*)(dw2t + (size_t)n * 64);
#pragma unroll
  for (int ch = 0; ch < 8; ch++) {
    const bf16x8 v = drow[ch];
#pragma unroll
    for (int e = 0; e < 8; e++) {
      const float b = bf2f((unsigned short)v[e]);
      const int col = ch * 8 + e;
#pragma unroll
      for (int r = 0; r < 4; r++) acc[r] = fmaf(twL[r][col], b, acc[r]);
    }
  }
  const float dpn = dp[n];
#pragma unroll
  for (int r = 0; r < 4; r++) {
    float wv = acc[r] + dpn;
    wv = fminf(fmaxf(wv, -9.72f), 2.27f);
    td[(size_t)(t0 + r) * HDIM + n] = expf(-expf(wv));
  }
}

// ---------- single local scan pass (+ fused decay: rt, Ptot) ----------
__global__ __launch_bounds__(256) void scan_local_kernel(const __hip_bfloat16* __restrict__ kb,
                                                         const __hip_bfloat16* __restrict__ rb,
                                                         const float* __restrict__ td,
                                                         const __hip_bfloat16* __restrict__ vb,
                                                         float* __restrict__ wkv,
                                                         float* __restrict__ qT,
                                                         __hip_bfloat16* __restrict__ rt,
                                                         float* __restrict__ Ptot) {
  const int blk = blockIdx.x;           // c*NHEAD + h
  const int c = blk >> 5, h = blk & 31;
  const int w = threadIdx.x >> 6;       // j-quarter 0..3
  const int i = threadIdx.x & 63;       // lane = output row
  __shared__ float plds[2][4][64];

  float s[16];
#pragma unroll
  for (int q = 0; q < 16; q++) s[q] = 0.f;

  const int t0 = c * CT;
  const int hb = h * HSZ;
  const int jSelf = w * 16 + (i & 15);  // this thread's decay-tracked column
  float Aself = 1.f;
  __hip_bfloat16* rtbase = rt + (((size_t)c * NHEAD + h) * CT) * HSZ + jSelf;

  for (int t = 0; t < CT; t++) {
    const size_t rowb = (size_t)(t0 + t) * HDIM + hb;
    const unsigned* kw = (const unsigned*)(kb + rowb + w * 16);  // 8 dwords (uniform)
    const unsigned* rw = (const unsigned*)(rb + rowb + w * 16);
    const float* tdw = td + rowb + w * 16;
    const float vi = __bfloat162float(vb[rowb + i]);
    float p = 0.f;
#pragma unroll
    for (int m = 0; m < 8; m++) {
      const unsigned kpair = kw[m];
      const unsigned rpair = rw[m];
      const float k0 = __builtin_bit_cast(float, kpair << 16);
      const float k1 = __builtin_bit_cast(float, kpair & 0xffff0000u);
      const float r0 = __builtin_bit_cast(float, rpair << 16);
      const float r1 = __builtin_bit_cast(float, rpair & 0xffff0000u);
      const float td0 = tdw[2 * m];
      const float td1 = tdw[2 * m + 1];
      const float kv0 = vi * k0;
      const float kv1 = vi * k1;
      p = fmaf(r0, s[2 * m], p);
      p = fmaf(r1, s[2 * m + 1], p);
      s[2 * m] = fmaf(s[2 * m], td0, kv0);
      s[2 * m + 1] = fmaf(s[2 * m + 1], td1, kv1);
    }
    // fused decay: rt[t][jSelf] = r * cumA(t-1); A *= td
    const float rself = __bfloat162float(rb[rowb + jSelf]);
    if (i < 16) rtbase[(size_t)t * HSZ] = __float2bfloat16(rself * Aself);
    Aself *= td[rowb + jSelf];

    plds[t & 1][w][i] = p;
    __syncthreads();
    if (w == 0) {
      wkv[rowb + i] = plds[t & 1][0][i] + plds[t & 1][1][i] +
                      plds[t & 1][2][i] + plds[t & 1][3][i];
    }
  }
  if (i < 16) Ptot[((size_t)c * NHEAD + h) * HSZ + jSelf] = Aself;
  float* qbase = qT + (((size_t)c * NHEAD + h) * HSZ + w * 16) * HSZ + i;
#pragma unroll
  for (int q = 0; q < 16; q++) qbase[(size_t)q * HSZ] = s[q];
}

// ---------- sequential chunk combine: s0b (bf16) per chunk + s2out ----------
__global__ __launch_bounds__(64) void scan_s_kernel(const float* __restrict__ qT,
                                                    const float* __restrict__ Ptot,
                                                    const float* __restrict__ s2in,
                                                    __hip_bfloat16* __restrict__ s0b,
                                                    float* __restrict__ s2out) {
  const int h = blockIdx.x, i = blockIdx.y, j = threadIdx.x;
  float s = s2in[((size_t)h * HSZ + i) * HSZ + j];
#pragma unroll 4
  for (int c = 0; c < NC; c++) {
    s0b[(((size_t)c * NHEAD + h) * HSZ + i) * HSZ + j] = __float2bfloat16(s);
    s = fmaf(s, Ptot[((size_t)c * NHEAD + h) * HSZ + j],
             qT[(((size_t)c * NHEAD + h) * HSZ + j) * HSZ + i]);
  }
  s2out[((size_t)h * HSZ + i) * HSZ + j] = s;
}

// ---------- group norm (+ fused correction dot + diag term) + gate ----------
__global__ __launch_bounds__(256) void gnorm_kernel(const float* __restrict__ wkv,
                                                    const __hip_bfloat16* __restrict__ kb,
                                                    const __hip_bfloat16* __restrict__ rb,
                                                    const float* __restrict__ tf,
                                                    const __hip_bfloat16* __restrict__ vb,
                                                    const __hip_bfloat16* __restrict__ gb,
                                                    const __hip_bfloat16* __restrict__ rt,
                                                    const __hip_bfloat16* __restrict__ s0b,
                                                    const float* __restrict__ lnw,
                                                    const float* __restrict__ lnb,
                                                    __hip_bfloat16* __restrict__ yA) {
  const int t = blockIdx.x;
  const int wid = threadIdx.x >> 6, j = threadIdx.x & 63;
  const int h = blockIdx.y * 4 + wid;
  const size_t idx = (size_t)t * HDIM + h * HSZ + j;
  const int c = t >> 5, tc = t & 31;  // CT = 32

  // correction: sum_k rt[c][h][tc][k] * s0b[c][h][j][k]
  const bf16x8* rtrow = (const bf16x8*)(rt + (((size_t)c * NHEAD + h) * CT + tc) * HSZ);
  const bf16x8* srow = (const bf16x8*)(s0b + (((size_t)c * NHEAD + h) * HSZ + j) * HSZ);
  float corr = 0.f;
#pragma unroll
  for (int ch = 0; ch < 8; ch++) {
    const bf16x8 rv = rtrow[ch];
    const bf16x8 sv = srow[ch];
#pragma unroll
    for (int e = 0; e < 8; e++)
      corr = fmaf(bf2f((unsigned short)rv[e]), bf2f((unsigned short)sv[e]), corr);
  }

  const float kj = __bfloat162float(kb[idx]);
  const float rj = __bfloat162float(rb[idx]);
  const float dg = waveRedSum(rj * tf[h * HSZ + j] * kj);
  const float v = wkv[idx] + corr + dg * __bfloat162float(vb[idx]);
  const float mu = waveRedSum(v) * (1.f / HSZ);
  const float d = v - mu;
  const float var = waveRedSum(d * d) * (1.f / HSZ);
  float y = d * rsqrtf(var + 1e-5f);
  y = y * lnw[h * HSZ + j] + lnb[h * HSZ + j];
  y *= __bfloat162float(gb[idx]);
  yA[idx] = __float2bfloat16(y);
}

extern "C" void kernel_launch(void* const* d_in, const int* in_sizes, int n_in,
                              void* d_out, int out_size, void* d_ws, size_t ws_size,
                              hipStream_t stream) {
  (void)in_sizes; (void)n_in; (void)out_size; (void)ws_size;

  const float* x    = (const float*)d_in[0];
  const float* s1   = (const float*)d_in[1];
  const float* s2   = (const float*)d_in[2];
  const float* ln1w = (const float*)d_in[3];
  const float* ln1b = (const float*)d_in[4];
  const float* tmx  = (const float*)d_in[5];
  const float* tmaa = (const float*)d_in[6];
  const float* w1   = (const float*)d_in[7];
  const float* w2   = (const float*)d_in[8];
  const float* dw1  = (const float*)d_in[9];
  const float* dw2  = (const float*)d_in[10];
  const float* dp   = (const float*)d_in[11];
  const float* tf   = (const float*)d_in[12];
  const float* Wr   = (const float*)d_in[13];
  const float* Wk   = (const float*)d_in[14];
  const float* Wv   = (const float*)d_in[15];
  const float* Wg   = (const float*)d_in[16];
  const float* Wo   = (const float*)d_in[17];
  const float* lnxw = (const float*)d_in[18];
  const float* lnxb = (const float*)d_in[19];

  float* out0  = (float*)d_out;
  float* s1out = out0 + (size_t)TLEN * HDIM;
  float* s2out = s1out + HDIM;

  char* wp = (char*)d_ws;
  size_t off = 0;
  auto carve = [&](size_t bytes) -> void* {
    void* r = wp + off;
    off += (bytes + 255) & ~(size_t)255;
    return r;
  };

  __hip_bfloat16* wrt  = (__hip_bfloat16*)carve((size_t)HDIM * HDIM * 2);
  __hip_bfloat16* wkt  = (__hip_bfloat16*)carve((size_t)HDIM * HDIM * 2);
  __hip_bfloat16* wvt  = (__hip_bfloat16*)carve((size_t)HDIM * HDIM * 2);
  __hip_bfloat16* wgt  = (__hip_bfloat16*)carve((size_t)HDIM * HDIM * 2);
  __hip_bfloat16* wot  = (__hip_bfloat16*)carve((size_t)HDIM * HDIM * 2);
  __hip_bfloat16* w1t  = (__hip_bfloat16*)carve((size_t)160 * HDIM * 2);
  __hip_bfloat16* dw1t = (__hip_bfloat16*)carve((size_t)64 * HDIM * 2);
  __hip_bfloat16* dw2t = (__hip_bfloat16*)carve((size_t)HDIM * 64 * 2);
  float* xl            = (float*)carve((size_t)THE * 4);
  __hip_bfloat16* xxx  = (__hip_bfloat16*)carve((size_t)THE * 2);
  float* t5            = (float*)carve((size_t)TLEN * 160 * 4);
  __hip_bfloat16* x5b  = (__hip_bfloat16*)carve((size_t)5 * THE * 2);
  __hip_bfloat16* rb   = (__hip_bfloat16*)carve((size_t)THE * 2);
  __hip_bfloat16* kb   = (__hip_bfloat16*)carve((size_t)THE * 2);
  __hip_bfloat16* vb   = (__hip_bfloat16*)carve((size_t)THE * 2);
  __hip_bfloat16* gb   = (__hip_bfloat16*)carve((size_t)THE * 2);
  __hip_bfloat16* tw   = (__hip_bfloat16*)carve((size_t)TLEN * 64 * 2);
  float* td            = (float*)carve((size_t)THE * 4);
  float* wkv           = (float*)carve((size_t)THE * 4);
  __hip_bfloat16* yA   = (__hip_bfloat16*)carve((size_t)THE * 2);

  // Aliased scratch (all regions dead at time of use):
  //   qT   (16MB) <- x5b       (dead after G4; used in scan stage)
  //   rt   ( 4MB) <- xl        (dead after mix; rt read through gnorm)
  //   s0b  ( 8MB) <- td        (td dead after scan_local; s0b read through gnorm)
  //   Ptot (256KB)<- t5        (dead after mix)
  //   pg1  (5.2MB)<- td region (free until tdcalc writes td)
  //   pg4  ( 2MB) <- xxx       (dead after G1)
  //   pg6  (32MB) <- x5b..vb   (x5b/qT dead after scan_s; rb/kb/vb read by gnorm
  //                             BEFORE G6 runs -- pg6 written only in G6)
  float* qT            = (float*)x5b;
  __hip_bfloat16* rt   = (__hip_bfloat16*)xl;
  __hip_bfloat16* s0b  = (__hip_bfloat16*)td;
  float* Ptot          = (float*)t5;
  float* pg1           = (float*)td;
  float* pg4           = (float*)xxx;
  float* pg6           = (float*)x5b;

  // K0: convert + transpose all GEMM weights to bf16 [N][K]
  TrArgs ta;
  const float* srcs[8] = {Wr, Wk, Wv, Wg, Wo, w1, dw1, dw2};
  __hip_bfloat16* dsts[8] = {wrt, wkt, wvt, wgt, wot, w1t, dw1t, dw2t};
  const int Rs[8] = {HDIM, HDIM, HDIM, HDIM, HDIM, HDIM, HDIM, 64};
  const int Cs[8] = {HDIM, HDIM, HDIM, HDIM, HDIM, 160, 64, HDIM};
  for (int z = 0; z < 8; z++) { ta.src[z] = srcs[z]; ta.dst[z] = dsts[z]; ta.R[z] = Rs[z]; ta.C[z] = Cs[z]; }
  transp_kernel<<<dim3(64, 64, 8), 256, 0, stream>>>(ta);

  // K1: layernorm + token-shift fused -> xl, xxx
  ln1_kernel<<<dim3(TLEN), 256, 0, stream>>>(x, ln1w, ln1b, s1, tmx, xl, xxx, s1out);

  // G1: t5 = tanh(xxx @ w1)  (M=1024, N=160, K=2048) -- split-K=8
  {
    GemmArgs g{};
    for (int ks = 0; ks < 8; ks++) {
      g.A[ks] = xxx + ks * 256;
      g.B[ks] = w1t + ks * 256;
      g.C[ks] = pg1 + (size_t)ks * TLEN * 160;
      g.epi[ks] = 6;
    }
    g.M = TLEN; g.N = 160; g.K = 256; g.Ks = HDIM;
    gemm_bt<<<dim3(TLEN / 128, 2, 8), 256, 0, stream>>>(g);
    comb8_tanh_f32<<<dim3(TLEN * 160 / 256), 256, 0, stream>>>(pg1, t5, TLEN * 160);
  }

  // K4: mix + x5 (5 planes, bf16)
  mix_kernel<<<dim3(HDIM / 256, TLEN / 8), 256, 0, stream>>>(t5, xl, s1, w2, tmaa, x5b);

  // G2: r, k, v, g  (batched z=4)
  {
    GemmArgs g{};
    g.A[0] = x5b + (size_t)3 * THE; g.B[0] = wrt; g.C[0] = rb; g.epi[0] = 0;
    g.A[1] = x5b + (size_t)1 * THE; g.B[1] = wkt; g.C[1] = kb; g.epi[1] = 0;
    g.A[2] = x5b + (size_t)2 * THE; g.B[2] = wvt; g.C[2] = vb; g.epi[2] = 0;
    g.A[3] = x5b + (size_t)4 * THE; g.B[3] = wgt; g.C[3] = gb; g.epi[3] = 1;
    g.M = TLEN; g.N = HDIM; g.K = HDIM; g.Ks = HDIM;
    gemm_bt<<<dim3(TLEN / 128, HDIM / 128, 4), 256, 0, stream>>>(g);
  }

  // G4: tw = tanh(mw @ dw1)  (N=64) -- split-K=8
  {
    GemmArgs g{};
    for (int ks = 0; ks < 8; ks++) {
      g.A[ks] = x5b + ks * 256;          // plane 0 = mw
      g.B[ks] = dw1t + ks * 256;
      g.C[ks] = pg4 + (size_t)ks * TLEN * 64;
      g.epi[ks] = 6;
    }
    g.M = TLEN; g.N = 64; g.K = 256; g.Ks = HDIM;
    gemm_bt<<<dim3(TLEN / 128, 1, 8), 256, 0, stream>>>(g);
    comb8_tanh_bf16<<<dim3(TLEN * 64 / 256), 256, 0, stream>>>(pg4, tw, TLEN * 64);
  }

  // G5': td = exp(-exp(clip(tw @ dw2 + p))) -- dedicated memory-bound kernel
  tdcalc_kernel<<<dim3(TLEN / 4, HDIM / 256), 256, 0, stream>>>(tw, dw2t, dp, td);

  // Scan stage: local pass (+decay fused), chunk combine; correction folded into gnorm
  scan_local_kernel<<<dim3(NC * NHEAD), 256, 0, stream>>>(kb, rb, td, vb, wkv, qT, rt, Ptot);
  scan_s_kernel<<<dim3(NHEAD, HSZ), 64, 0, stream>>>(qT, Ptot, s2, s0b, s2out);

  // K7: group-norm (+correction dot +diag term) + gate -> yA (bf16)
  gnorm_kernel<<<dim3(TLEN, NHEAD / 4), 256, 0, stream>>>(wkv, kb, rb, tf, vb, gb, rt, s0b,
                                                          lnxw, lnxb, yA);

  // G6: out = x + yA @ W_o  -- split-K=4 (512 blocks = 2 blocks/CU TLP threshold)
  {
    GemmArgs g{};
    for (int ks = 0; ks < 4; ks++) {
      g.A[ks] = yA + ks * 512;
      g.B[ks] = wot + ks * 512;
      g.C[ks] = pg6 + (size_t)ks * THE;
      g.epi[ks] = 6;
    }
    g.M = TLEN; g.N = HDIM; g.K = 512; g.Ks = HDIM;
    gemm_bt<<<dim3(TLEN / 128, HDIM / 128, 4), 256, 0, stream>>>(g);
    comb4_resid<<<dim3(THE / 4 / 256), 256, 0, stream>>>(pg6, x, out0);
  }
}

// Round 14
// 271.317 us; speedup vs baseline: 1.1533x; 1.1533x over previous
//
#include <hip/hip_runtime.h>
#include <hip/hip_bf16.h>
#include <math.h>

#define TLEN 1024
#define HDIM 2048
#define NHEAD 32
#define HSZ 64
#define THE (TLEN * HDIM)
#define NC 32          // scan chunks
#define CT (TLEN / NC) // 32 timesteps per chunk

typedef __attribute__((ext_vector_type(8))) short bf16x8;
typedef __attribute__((ext_vector_type(4))) float f32x4;

__device__ __forceinline__ float waveRedSum(float v) {
#pragma unroll
  for (int off = 32; off > 0; off >>= 1) v += __shfl_xor(v, off, 64);
  return v;
}

__device__ __forceinline__ float bf2f(unsigned short u) {
  return __builtin_bit_cast(float, (unsigned)u << 16);
}

__device__ __forceinline__ void gll16(const __hip_bfloat16* g, __hip_bfloat16* l) {
  __builtin_amdgcn_global_load_lds(
      (const __attribute__((address_space(1))) void*)g,
      (__attribute__((address_space(3))) void*)l, 16, 0, 0);
}

// ---------- weight convert + transpose: src f32 [R][C] -> dst bf16 [C][R] ----------
struct TrArgs {
  const float* src[8];
  __hip_bfloat16* dst[8];
  int R[8];
  int C[8];
};

__global__ __launch_bounds__(256) void transp_kernel(TrArgs ta) {
  const int z = blockIdx.z;
  const int R = ta.R[z], C = ta.C[z];
  const int c0 = blockIdx.x * 32, r0 = blockIdx.y * 32;
  if (c0 >= C || r0 >= R) return;
  __shared__ float tile[32][33];
  const int tx = threadIdx.x & 31, ty = threadIdx.x >> 5;
  const float* src = ta.src[z];
  __hip_bfloat16* dst = ta.dst[z];
#pragma unroll
  for (int i = 0; i < 4; i++)
    tile[ty + i * 8][tx] = src[(size_t)(r0 + ty + i * 8) * C + c0 + tx];
  __syncthreads();
#pragma unroll
  for (int i = 0; i < 4; i++)
    dst[(size_t)(c0 + ty + i * 8) * R + r0 + tx] = __float2bfloat16(tile[tx][ty + i * 8]);
}

// ---------- LayerNorm (rows t and t-1) + token-shift fused ----------
__global__ __launch_bounds__(256) void ln1_kernel(const float* __restrict__ x,
                                                  const float* __restrict__ w,
                                                  const float* __restrict__ b,
                                                  const float* __restrict__ s1,
                                                  const float* __restrict__ tmx,
                                                  float* __restrict__ xl,
                                                  __hip_bfloat16* __restrict__ xxx,
                                                  float* __restrict__ s1out) {
  const int t = blockIdx.x;
  const int tid = threadIdx.x;
  const int wid = tid >> 6, lane = tid & 63;
  const float4* xr = (const float4*)(x + (size_t)t * HDIM);
  const float4* xp = (const float4*)(x + (size_t)(t > 0 ? t - 1 : 0) * HDIM);
  float4 a = xr[tid], c = xr[tid + 256];
  float4 ap = xp[tid], cp = xp[tid + 256];
  float va[8] = {a.x, a.y, a.z, a.w, c.x, c.y, c.z, c.w};
  float vp[8] = {ap.x, ap.y, ap.z, ap.w, cp.x, cp.y, cp.z, cp.w};
  float sum = 0.f, sump = 0.f;
#pragma unroll
  for (int i = 0; i < 8; i++) { sum += va[i]; sump += vp[i]; }
  sum = waveRedSum(sum);
  sump = waveRedSum(sump);
  __shared__ float red[16];
  if (lane == 0) { red[wid] = sum; red[8 + wid] = sump; }
  __syncthreads();
  const float mu = (red[0] + red[1] + red[2] + red[3]) * (1.f / HDIM);
  const float mup = (red[8] + red[9] + red[10] + red[11]) * (1.f / HDIM);
  float vs = 0.f, vsp = 0.f;
#pragma unroll
  for (int i = 0; i < 8; i++) {
    float d = va[i] - mu; vs += d * d;
    float dp = vp[i] - mup; vsp += dp * dp;
  }
  vs = waveRedSum(vs);
  vsp = waveRedSum(vsp);
  if (lane == 0) { red[4 + wid] = vs; red[12 + wid] = vsp; }
  __syncthreads();
  const float rstd = rsqrtf((red[4] + red[5] + red[6] + red[7]) * (1.f / HDIM) + 1e-5f);
  const float rstdp = rsqrtf((red[12] + red[13] + red[14] + red[15]) * (1.f / HDIM) + 1e-5f);
  float* xrow = xl + (size_t)t * HDIM;
  __hip_bfloat16* xxrow = xxx + (size_t)t * HDIM;
#pragma unroll
  for (int i = 0; i < 8; i++) {
    const int idx = (i < 4) ? (4 * tid + i) : (1024 + 4 * tid + (i - 4));
    const float wv = w[idx], bv = b[idx];
    const float cur = (va[i] - mu) * rstd * wv + bv;
    const float past = (t > 0) ? (vp[i] - mup) * rstdp * wv + bv : s1[idx];
    xrow[idx] = cur;
    xxrow[idx] = __float2bfloat16(cur + (past - cur) * tmx[idx]);
    if (t == TLEN - 1) s1out[idx] = cur;
  }
}

// ---------- mix: x5[f] = xl + sx * (t5[f] @ w2[f] + time_maa[f]) ----------
__global__ __launch_bounds__(256) void mix_kernel(const float* __restrict__ t5,
                                                  const float* __restrict__ xl,
                                                  const float* __restrict__ s1,
                                                  const float* __restrict__ w2,
                                                  const float* __restrict__ maa,
                                                  __hip_bfloat16* __restrict__ x5b) {
  const int h = blockIdx.x * 256 + threadIdx.x;
  const int t0 = blockIdx.y * 8;
  __shared__ float t5L[8 * 160];
  for (int i = threadIdx.x; i < 8 * 160; i += 256) {
    const int rr = i / 160, cc = i - rr * 160;
    t5L[i] = t5[(size_t)(t0 + rr) * 160 + cc];
  }
  __syncthreads();
  float mixv[8][5];
#pragma unroll
  for (int ts = 0; ts < 8; ts++)
#pragma unroll
    for (int f = 0; f < 5; f++) mixv[ts][f] = 0.f;
#pragma unroll
  for (int f = 0; f < 5; f++) {
#pragma unroll 4
    for (int m = 0; m < 32; m++) {
      const float w2v = w2[(size_t)(f * 32 + m) * HDIM + h];
#pragma unroll
      for (int ts = 0; ts < 8; ts++) mixv[ts][f] += t5L[ts * 160 + f * 32 + m] * w2v;
    }
  }
#pragma unroll
  for (int ts = 0; ts < 8; ts++) {
    const int t = t0 + ts;
    const float cur = xl[(size_t)t * HDIM + h];
    const float past = (t > 0) ? xl[(size_t)(t - 1) * HDIM + h] : s1[h];
    const float sx = past - cur;
#pragma unroll
    for (int f = 0; f < 5; f++) {
      const float v = cur + sx * (mixv[ts][f] + maa[(size_t)f * HDIM + h]);
      x5b[(size_t)f * THE + (size_t)t * HDIM + h] = __float2bfloat16(v);
    }
  }
}

// ---------- batched MFMA GEMM: C[z] = epi( A[z](MxK) @ Bt[z](NxK)^T ) ----------
// BK=64, double-buffered LDS, counted-vmcnt pipeline, conflict-free swizzle.
struct GemmArgs {
  const __hip_bfloat16* A[8];
  const __hip_bfloat16* B[8];
  void* C[8];
  const float* aux[8];
  int epi[8];
  int M, N, K, Ks;
};

__global__ __launch_bounds__(256) void gemm_bt(GemmArgs ga) {
  const int z = blockIdx.z;
  const __hip_bfloat16* __restrict__ A = ga.A[z];
  const __hip_bfloat16* __restrict__ Bt = ga.B[z];
  const int N = ga.N, K = ga.K, Ks = ga.Ks;
  const int epi = ga.epi[z];
  const float* __restrict__ aux = ga.aux[z];
  void* Cz = ga.C[z];

  __shared__ __align__(16) __hip_bfloat16 As[2][128 * 64];
  __shared__ __align__(16) __hip_bfloat16 Bs[2][128 * 64];

  const int tid = threadIdx.x;
  const int wid = tid >> 6;
  const int lane = tid & 63;

  int bx = blockIdx.x, by = blockIdx.y;
  if (gridDim.x == 8 && gridDim.y == 16) {
    const int flat = bx + 8 * by;
    const int xcd = flat & 7, rem = flat >> 3;
    bx = rem & 7;
    by = xcd + 8 * (rem >> 3);
  }
  const int m0 = bx * 128;
  const int n0 = by * 128;
  const int wr = wid >> 1, wc = wid & 1;

  const int srow = lane >> 3;
  const int chunkS = (lane & 7) ^ srow;
  const __hip_bfloat16* aSrcQ[4];
  const __hip_bfloat16* bSrcQ[4];
#pragma unroll
  for (int q = 0; q < 4; q++) {
    const int arow = wid * 32 + q * 8 + srow;
    int brow = n0 + arow; if (brow > N - 1) brow = N - 1;
    aSrcQ[q] = A + (size_t)(m0 + arow) * Ks + chunkS * 8;
    bSrcQ[q] = Bt + (size_t)brow * Ks + chunkS * 8;
  }

  f32x4 acc[4][4];
#pragma unroll
  for (int m = 0; m < 4; m++)
#pragma unroll
    for (int n = 0; n < 4; n++) acc[m][n] = 0.f;

  const int lr = lane & 15;
  const int cbase = lane >> 4;
  int aoffk[2], boffk[2];
#pragma unroll
  for (int kg = 0; kg < 2; kg++) {
    const int phys = (kg * 4 + cbase) ^ (lr & 7);
    aoffk[kg] = (wr * 64 + lr) * 64 + phys * 8;
    boffk[kg] = (wc * 64 + lr) * 64 + phys * 8;
  }

#define STAGE(BUF, KT)                                              \
  do {                                                              \
    _Pragma("unroll") for (int q = 0; q < 4; q++) {                 \
      gll16(aSrcQ[q] + (KT), &As[BUF][(wid * 32 + q * 8) * 64]);    \
      gll16(bSrcQ[q] + (KT), &Bs[BUF][(wid * 32 + q * 8) * 64]);    \
    }                                                               \
  } while (0)

  STAGE(0, 0);
  int cur = 0;
  for (int kt = 0; kt < K; kt += 64) {
    const bool more = (kt + 64 < K);
    if (more) {
      STAGE(cur ^ 1, kt + 64);
      asm volatile("s_waitcnt vmcnt(8)" ::: "memory");
    } else {
      asm volatile("s_waitcnt vmcnt(0)" ::: "memory");
    }
    __builtin_amdgcn_s_barrier();
#pragma unroll
    for (int kg = 0; kg < 2; kg++) {
      bf16x8 af[4], bfv[4];
#pragma unroll
      for (int m = 0; m < 4; m++) af[m] = *(const bf16x8*)&As[cur][aoffk[kg] + m * 16 * 64];
#pragma unroll
      for (int n = 0; n < 4; n++) bfv[n] = *(const bf16x8*)&Bs[cur][boffk[kg] + n * 16 * 64];
#pragma unroll
      for (int m = 0; m < 4; m++)
#pragma unroll
        for (int n = 0; n < 4; n++)
          acc[m][n] = __builtin_amdgcn_mfma_f32_16x16x32_bf16(af[m], bfv[n], acc[m][n], 0, 0, 0);
    }
    __builtin_amdgcn_s_barrier();
    cur ^= 1;
  }
#undef STAGE

  const int r4 = (lane >> 4) * 4;
#pragma unroll
  for (int m = 0; m < 4; m++) {
#pragma unroll
    for (int n = 0; n < 4; n++) {
      const int gn = n0 + wc * 64 + n * 16 + lr;
      if (gn < N) {
#pragma unroll
        for (int r = 0; r < 4; r++) {
          const int gm = m0 + wr * 64 + m * 16 + r4 + r;
          const size_t idx = (size_t)gm * N + gn;
          const float v = acc[m][n][r];
          switch (epi) {
            case 0: ((__hip_bfloat16*)Cz)[idx] = __float2bfloat16(v); break;
            case 1: ((__hip_bfloat16*)Cz)[idx] = __float2bfloat16(v / (1.f + expf(-v))); break;
            case 2: ((float*)Cz)[idx] = tanhf(v); break;
            case 3: ((__hip_bfloat16*)Cz)[idx] = __float2bfloat16(tanhf(v)); break;
            case 5: ((float*)Cz)[idx] = v + aux[idx]; break;
            case 6: ((float*)Cz)[idx] = v; break;
          }
        }
      }
    }
  }
}

// ---------- split-K combines ----------
__global__ __launch_bounds__(256) void comb8_tanh_f32(const float* __restrict__ p,
                                                      float* __restrict__ o, int n) {
  const int i = blockIdx.x * 256 + threadIdx.x;
  float s = 0.f;
#pragma unroll
  for (int k = 0; k < 8; k++) s += p[(size_t)k * n + i];
  o[i] = tanhf(s);
}

__global__ __launch_bounds__(256) void comb8_tanh_bf16(const float* __restrict__ p,
                                                       __hip_bfloat16* __restrict__ o, int n) {
  const int i = blockIdx.x * 256 + threadIdx.x;
  float s = 0.f;
#pragma unroll
  for (int k = 0; k < 8; k++) s += p[(size_t)k * n + i];
  o[i] = __float2bfloat16(tanhf(s));
}

__global__ __launch_bounds__(256) void comb4_resid(const float* __restrict__ p,
                                                   const float* __restrict__ x,
                                                   float* __restrict__ o) {
  const int i = blockIdx.x * 256 + threadIdx.x;
  const float4 a = ((const float4*)p)[i];
  const float4 b = ((const float4*)(p + THE))[i];
  const float4 c = ((const float4*)(p + 2 * (size_t)THE))[i];
  const float4 d = ((const float4*)(p + 3 * (size_t)THE))[i];
  const float4 e = ((const float4*)x)[i];
  ((float4*)o)[i] = make_float4(a.x + b.x + c.x + d.x + e.x,
                                a.y + b.y + c.y + d.y + e.y,
                                a.z + b.z + c.z + d.z + e.z,
                                a.w + b.w + c.w + d.w + e.w);
}

// ---------- td = exp(-exp(clip(tw @ dw2 + dp)))  -- K=64 dot, memory-bound ----------
__global__ __launch_bounds__(256) void tdcalc_kernel(const __hip_bfloat16* __restrict__ tw,
                                                     const __hip_bfloat16* __restrict__ dw2t,
                                                     const float* __restrict__ dp,
                                                     float* __restrict__ td) {
  const int t0 = blockIdx.x * 4;
  const int n = blockIdx.y * 256 + threadIdx.x;
  __shared__ float twL[4][64];
  {
    const int row = threadIdx.x >> 6, col = threadIdx.x & 63;
    twL[row][col] = __bfloat162float(tw[(size_t)(t0 + row) * 64 + col]);
  }
  __syncthreads();
  float acc[4] = {0.f, 0.f, 0.f, 0.f};
  const bf16x8* drow = (const bf16x8*)(dw2t + (size_t)n * 64);
#pragma unroll
  for (int ch = 0; ch < 8; ch++) {
    const bf16x8 v = drow[ch];
#pragma unroll
    for (int e = 0; e < 8; e++) {
      const float b = bf2f((unsigned short)v[e]);
      const int col = ch * 8 + e;
#pragma unroll
      for (int r = 0; r < 4; r++) acc[r] = fmaf(twL[r][col], b, acc[r]);
    }
  }
  const float dpn = dp[n];
#pragma unroll
  for (int r = 0; r < 4; r++) {
    float wv = acc[r] + dpn;
    wv = fminf(fmaxf(wv, -9.72f), 2.27f);
    td[(size_t)(t0 + r) * HDIM + n] = expf(-expf(wv));
  }
}

// ---------- single local scan pass (+ fused decay: rt, Ptot) ----------
__global__ __launch_bounds__(256) void scan_local_kernel(const __hip_bfloat16* __restrict__ kb,
                                                         const __hip_bfloat16* __restrict__ rb,
                                                         const float* __restrict__ td,
                                                         const __hip_bfloat16* __restrict__ vb,
                                                         float* __restrict__ wkv,
                                                         float* __restrict__ qT,
                                                         __hip_bfloat16* __restrict__ rt,
                                                         float* __restrict__ Ptot) {
  const int blk = blockIdx.x;           // c*NHEAD + h
  const int c = blk >> 5, h = blk & 31;
  const int w = threadIdx.x >> 6;       // j-quarter 0..3
  const int i = threadIdx.x & 63;       // lane = output row
  __shared__ float plds[2][4][64];

  float s[16];
#pragma unroll
  for (int q = 0; q < 16; q++) s[q] = 0.f;

  const int t0 = c * CT;
  const int hb = h * HSZ;
  const int jSelf = w * 16 + (i & 15);  // this thread's decay-tracked column
  float Aself = 1.f;
  __hip_bfloat16* rtbase = rt + (((size_t)c * NHEAD + h) * CT) * HSZ + jSelf;

  for (int t = 0; t < CT; t++) {
    const size_t rowb = (size_t)(t0 + t) * HDIM + hb;
    const unsigned* kw = (const unsigned*)(kb + rowb + w * 16);  // 8 dwords (uniform)
    const unsigned* rw = (const unsigned*)(rb + rowb + w * 16);
    const float* tdw = td + rowb + w * 16;
    const float vi = __bfloat162float(vb[rowb + i]);
    float p = 0.f;
#pragma unroll
    for (int m = 0; m < 8; m++) {
      const unsigned kpair = kw[m];
      const unsigned rpair = rw[m];
      const float k0 = __builtin_bit_cast(float, kpair << 16);
      const float k1 = __builtin_bit_cast(float, kpair & 0xffff0000u);
      const float r0 = __builtin_bit_cast(float, rpair << 16);
      const float r1 = __builtin_bit_cast(float, rpair & 0xffff0000u);
      const float td0 = tdw[2 * m];
      const float td1 = tdw[2 * m + 1];
      const float kv0 = vi * k0;
      const float kv1 = vi * k1;
      p = fmaf(r0, s[2 * m], p);
      p = fmaf(r1, s[2 * m + 1], p);
      s[2 * m] = fmaf(s[2 * m], td0, kv0);
      s[2 * m + 1] = fmaf(s[2 * m + 1], td1, kv1);
    }
    // fused decay: rt[t][jSelf] = r * cumA(t-1); A *= td
    const float rself = __bfloat162float(rb[rowb + jSelf]);
    if (i < 16) rtbase[(size_t)t * HSZ] = __float2bfloat16(rself * Aself);
    Aself *= td[rowb + jSelf];

    plds[t & 1][w][i] = p;
    __syncthreads();
    if (w == 0) {
      wkv[rowb + i] = plds[t & 1][0][i] + plds[t & 1][1][i] +
                      plds[t & 1][2][i] + plds[t & 1][3][i];
    }
  }
  if (i < 16) Ptot[((size_t)c * NHEAD + h) * HSZ + jSelf] = Aself;
  float* qbase = qT + (((size_t)c * NHEAD + h) * HSZ + w * 16) * HSZ + i;
#pragma unroll
  for (int q = 0; q < 16; q++) qbase[(size_t)q * HSZ] = s[q];
}

// ---------- sequential chunk combine: s0b (bf16) per chunk + s2out ----------
__global__ __launch_bounds__(64) void scan_s_kernel(const float* __restrict__ qT,
                                                    const float* __restrict__ Ptot,
                                                    const float* __restrict__ s2in,
                                                    __hip_bfloat16* __restrict__ s0b,
                                                    float* __restrict__ s2out) {
  const int h = blockIdx.x, i = blockIdx.y, j = threadIdx.x;
  float s = s2in[((size_t)h * HSZ + i) * HSZ + j];
#pragma unroll 4
  for (int c = 0; c < NC; c++) {
    s0b[(((size_t)c * NHEAD + h) * HSZ + i) * HSZ + j] = __float2bfloat16(s);
    s = fmaf(s, Ptot[((size_t)c * NHEAD + h) * HSZ + j],
             qT[(((size_t)c * NHEAD + h) * HSZ + j) * HSZ + i]);
  }
  s2out[((size_t)h * HSZ + i) * HSZ + j] = s;
}

// ---------- correction GEMM: wkv[c*CT+t][h][i] += sum_j rt[t][j] * s0b[i][j] ----------
__global__ __launch_bounds__(256) void corr_kernel(const __hip_bfloat16* __restrict__ rt,
                                                   const __hip_bfloat16* __restrict__ s0b,
                                                   float* __restrict__ wkv) {
  const int c = blockIdx.x, h = blockIdx.y;
  const int w = threadIdx.x >> 6;   // n-tile (i)
  const int lane = threadIdx.x & 63;
  const int lr = lane & 15, lk = (lane >> 4) * 8;
  const __hip_bfloat16* rbase = rt + (((size_t)c * NHEAD + h) * CT) * HSZ;
  const __hip_bfloat16* sbase = s0b + (((size_t)c * NHEAD + h) * HSZ) * HSZ;
  float* wbase = wkv + (size_t)(c * CT) * HDIM + h * HSZ;
#pragma unroll
  for (int mt = 0; mt < CT / 16; mt++) {
    f32x4 acc = {0.f, 0.f, 0.f, 0.f};
#pragma unroll
    for (int ks = 0; ks < 2; ks++) {
      bf16x8 af = *(const bf16x8*)(rbase + (size_t)(mt * 16 + lr) * HSZ + ks * 32 + lk);
      bf16x8 bf = *(const bf16x8*)(sbase + (size_t)(w * 16 + lr) * HSZ + ks * 32 + lk);
      acc = __builtin_amdgcn_mfma_f32_16x16x32_bf16(af, bf, acc, 0, 0, 0);
    }
    const int row = mt * 16 + (lane >> 4) * 4;
    const int col = w * 16 + lr;
#pragma unroll
    for (int r = 0; r < 4; r++)
      wbase[(size_t)(row + r) * HDIM + col] += acc[r];
  }
}

// ---------- group norm over HS (+diag wkv term) + scale/bias + gate ----------
__global__ __launch_bounds__(256) void gnorm_kernel(const float* __restrict__ wkv,
                                                    const __hip_bfloat16* __restrict__ kb,
                                                    const __hip_bfloat16* __restrict__ rb,
                                                    const float* __restrict__ tf,
                                                    const __hip_bfloat16* __restrict__ vb,
                                                    const __hip_bfloat16* __restrict__ gb,
                                                    const float* __restrict__ lnw,
                                                    const float* __restrict__ lnb,
                                                    __hip_bfloat16* __restrict__ yA) {
  const int t = blockIdx.x;
  const int wid = threadIdx.x >> 6, j = threadIdx.x & 63;
  const int h = blockIdx.y * 4 + wid;
  const size_t idx = (size_t)t * HDIM + h * HSZ + j;
  const float kj = __bfloat162float(kb[idx]);
  const float rj = __bfloat162float(rb[idx]);
  const float dg = waveRedSum(rj * tf[h * HSZ + j] * kj);
  const float v = wkv[idx] + dg * __bfloat162float(vb[idx]);
  const float mu = waveRedSum(v) * (1.f / HSZ);
  const float d = v - mu;
  const float var = waveRedSum(d * d) * (1.f / HSZ);
  float y = d * rsqrtf(var + 1e-5f);
  y = y * lnw[h * HSZ + j] + lnb[h * HSZ + j];
  y *= __bfloat162float(gb[idx]);
  yA[idx] = __float2bfloat16(y);
}

extern "C" void kernel_launch(void* const* d_in, const int* in_sizes, int n_in,
                              void* d_out, int out_size, void* d_ws, size_t ws_size,
                              hipStream_t stream) {
  (void)in_sizes; (void)n_in; (void)out_size; (void)ws_size;

  const float* x    = (const float*)d_in[0];
  const float* s1   = (const float*)d_in[1];
  const float* s2   = (const float*)d_in[2];
  const float* ln1w = (const float*)d_in[3];
  const float* ln1b = (const float*)d_in[4];
  const float* tmx  = (const float*)d_in[5];
  const float* tmaa = (const float*)d_in[6];
  const float* w1   = (const float*)d_in[7];
  const float* w2   = (const float*)d_in[8];
  const float* dw1  = (const float*)d_in[9];
  const float* dw2  = (const float*)d_in[10];
  const float* dp   = (const float*)d_in[11];
  const float* tf   = (const float*)d_in[12];
  const float* Wr   = (const float*)d_in[13];
  const float* Wk   = (const float*)d_in[14];
  const float* Wv   = (const float*)d_in[15];
  const float* Wg   = (const float*)d_in[16];
  const float* Wo   = (const float*)d_in[17];
  const float* lnxw = (const float*)d_in[18];
  const float* lnxb = (const float*)d_in[19];

  float* out0  = (float*)d_out;
  float* s1out = out0 + (size_t)TLEN * HDIM;
  float* s2out = s1out + HDIM;

  char* wp = (char*)d_ws;
  size_t off = 0;
  auto carve = [&](size_t bytes) -> void* {
    void* r = wp + off;
    off += (bytes + 255) & ~(size_t)255;
    return r;
  };

  __hip_bfloat16* wrt  = (__hip_bfloat16*)carve((size_t)HDIM * HDIM * 2);
  __hip_bfloat16* wkt  = (__hip_bfloat16*)carve((size_t)HDIM * HDIM * 2);
  __hip_bfloat16* wvt  = (__hip_bfloat16*)carve((size_t)HDIM * HDIM * 2);
  __hip_bfloat16* wgt  = (__hip_bfloat16*)carve((size_t)HDIM * HDIM * 2);
  __hip_bfloat16* wot  = (__hip_bfloat16*)carve((size_t)HDIM * HDIM * 2);
  __hip_bfloat16* w1t  = (__hip_bfloat16*)carve((size_t)160 * HDIM * 2);
  __hip_bfloat16* dw1t = (__hip_bfloat16*)carve((size_t)64 * HDIM * 2);
  __hip_bfloat16* dw2t = (__hip_bfloat16*)carve((size_t)HDIM * 64 * 2);
  float* xl            = (float*)carve((size_t)THE * 4);
  __hip_bfloat16* xxx  = (__hip_bfloat16*)carve((size_t)THE * 2);
  float* t5            = (float*)carve((size_t)TLEN * 160 * 4);
  __hip_bfloat16* x5b  = (__hip_bfloat16*)carve((size_t)5 * THE * 2);
  __hip_bfloat16* rb   = (__hip_bfloat16*)carve((size_t)THE * 2);
  __hip_bfloat16* kb   = (__hip_bfloat16*)carve((size_t)THE * 2);
  __hip_bfloat16* vb   = (__hip_bfloat16*)carve((size_t)THE * 2);
  __hip_bfloat16* gb   = (__hip_bfloat16*)carve((size_t)THE * 2);
  __hip_bfloat16* tw   = (__hip_bfloat16*)carve((size_t)TLEN * 64 * 2);
  float* td            = (float*)carve((size_t)THE * 4);
  float* wkv           = (float*)carve((size_t)THE * 4);
  __hip_bfloat16* yA   = (__hip_bfloat16*)carve((size_t)THE * 2);

  // Aliased scratch (all regions dead at time of use):
  //   qT   (16MB) <- x5b       (dead after G4; used in scan stage)
  //   rt   ( 4MB) <- xl        (dead after mix; rt read through corr)
  //   s0b  ( 8MB) <- td        (td dead after scan_local; s0b read through corr)
  //   Ptot (256KB)<- t5        (dead after mix)
  //   pg1  (5.2MB)<- td region (free until tdcalc writes td)
  //   pg4  ( 2MB) <- xxx       (dead after G1)
  //   pg6  (32MB) <- x5b..vb   (x5b/qT dead after scan_s; rb/kb/vb read by gnorm
  //                             BEFORE G6 runs -- pg6 written only in G6)
  float* qT            = (float*)x5b;
  __hip_bfloat16* rt   = (__hip_bfloat16*)xl;
  __hip_bfloat16* s0b  = (__hip_bfloat16*)td;
  float* Ptot          = (float*)t5;
  float* pg1           = (float*)td;
  float* pg4           = (float*)xxx;
  float* pg6           = (float*)x5b;

  // K0: convert + transpose all GEMM weights to bf16 [N][K]
  TrArgs ta;
  const float* srcs[8] = {Wr, Wk, Wv, Wg, Wo, w1, dw1, dw2};
  __hip_bfloat16* dsts[8] = {wrt, wkt, wvt, wgt, wot, w1t, dw1t, dw2t};
  const int Rs[8] = {HDIM, HDIM, HDIM, HDIM, HDIM, HDIM, HDIM, 64};
  const int Cs[8] = {HDIM, HDIM, HDIM, HDIM, HDIM, 160, 64, HDIM};
  for (int z = 0; z < 8; z++) { ta.src[z] = srcs[z]; ta.dst[z] = dsts[z]; ta.R[z] = Rs[z]; ta.C[z] = Cs[z]; }
  transp_kernel<<<dim3(64, 64, 8), 256, 0, stream>>>(ta);

  // K1: layernorm + token-shift fused -> xl, xxx
  ln1_kernel<<<dim3(TLEN), 256, 0, stream>>>(x, ln1w, ln1b, s1, tmx, xl, xxx, s1out);

  // G1: t5 = tanh(xxx @ w1)  (M=1024, N=160, K=2048) -- split-K=8
  {
    GemmArgs g{};
    for (int ks = 0; ks < 8; ks++) {
      g.A[ks] = xxx + ks * 256;
      g.B[ks] = w1t + ks * 256;
      g.C[ks] = pg1 + (size_t)ks * TLEN * 160;
      g.epi[ks] = 6;
    }
    g.M = TLEN; g.N = 160; g.K = 256; g.Ks = HDIM;
    gemm_bt<<<dim3(TLEN / 128, 2, 8), 256, 0, stream>>>(g);
    comb8_tanh_f32<<<dim3(TLEN * 160 / 256), 256, 0, stream>>>(pg1, t5, TLEN * 160);
  }

  // K4: mix + x5 (5 planes, bf16)
  mix_kernel<<<dim3(HDIM / 256, TLEN / 8), 256, 0, stream>>>(t5, xl, s1, w2, tmaa, x5b);

  // G2: r, k, v, g  (batched z=4)
  {
    GemmArgs g{};
    g.A[0] = x5b + (size_t)3 * THE; g.B[0] = wrt; g.C[0] = rb; g.epi[0] = 0;
    g.A[1] = x5b + (size_t)1 * THE; g.B[1] = wkt; g.C[1] = kb; g.epi[1] = 0;
    g.A[2] = x5b + (size_t)2 * THE; g.B[2] = wvt; g.C[2] = vb; g.epi[2] = 0;
    g.A[3] = x5b + (size_t)4 * THE; g.B[3] = wgt; g.C[3] = gb; g.epi[3] = 1;
    g.M = TLEN; g.N = HDIM; g.K = HDIM; g.Ks = HDIM;
    gemm_bt<<<dim3(TLEN / 128, HDIM / 128, 4), 256, 0, stream>>>(g);
  }

  // G4: tw = tanh(mw @ dw1)  (N=64) -- split-K=8
  {
    GemmArgs g{};
    for (int ks = 0; ks < 8; ks++) {
      g.A[ks] = x5b + ks * 256;          // plane 0 = mw
      g.B[ks] = dw1t + ks * 256;
      g.C[ks] = pg4 + (size_t)ks * TLEN * 64;
      g.epi[ks] = 6;
    }
    g.M = TLEN; g.N = 64; g.K = 256; g.Ks = HDIM;
    gemm_bt<<<dim3(TLEN / 128, 1, 8), 256, 0, stream>>>(g);
    comb8_tanh_bf16<<<dim3(TLEN * 64 / 256), 256, 0, stream>>>(pg4, tw, TLEN * 64);
  }

  // G5': td = exp(-exp(clip(tw @ dw2 + p))) -- dedicated memory-bound kernel
  tdcalc_kernel<<<dim3(TLEN / 4, HDIM / 256), 256, 0, stream>>>(tw, dw2t, dp, td);

  // Scan stage: local pass (+decay fused), chunk combine, MFMA correction
  scan_local_kernel<<<dim3(NC * NHEAD), 256, 0, stream>>>(kb, rb, td, vb, wkv, qT, rt, Ptot);
  scan_s_kernel<<<dim3(NHEAD, HSZ), 64, 0, stream>>>(qT, Ptot, s2, s0b, s2out);
  corr_kernel<<<dim3(NC, NHEAD), 256, 0, stream>>>(rt, s0b, wkv);

  // K7: group-norm (+diag term) + gate -> yA (bf16)
  gnorm_kernel<<<dim3(TLEN, NHEAD / 4), 256, 0, stream>>>(wkv, kb, rb, tf, vb, gb, lnxw, lnxb, yA);

  // G6: out = x + yA @ W_o  -- split-K=4 (512 blocks = 2 blocks/CU TLP threshold)
  {
    GemmArgs g{};
    for (int ks = 0; ks < 4; ks++) {
      g.A[ks] = yA + ks * 512;
      g.B[ks] = wot + ks * 512;
      g.C[ks] = pg6 + (size_t)ks * THE;
      g.epi[ks] = 6;
    }
    g.M = TLEN; g.N = HDIM; g.K = 512; g.Ks = HDIM;
    gemm_bt<<<dim3(TLEN / 128, HDIM / 128, 4), 256, 0, stream>>>(g);
    comb4_resid<<<dim3(THE / 4 / 256), 256, 0, stream>>>(pg6, x, out0);
  }
}

// Round 15
// 270.932 us; speedup vs baseline: 1.1549x; 1.0014x over previous
//
#include <hip/hip_runtime.h>
#include <hip/hip_bf16.h>
#include <math.h>

#define TLEN 1024
#define HDIM 2048
#define NHEAD 32
#define HSZ 64
#define THE (TLEN * HDIM)
#define NC 32          // scan chunks
#define CT (TLEN / NC) // 32 timesteps per chunk

typedef __attribute__((ext_vector_type(8))) short bf16x8;
typedef __attribute__((ext_vector_type(4))) float f32x4;

__device__ __forceinline__ float waveRedSum(float v) {
#pragma unroll
  for (int off = 32; off > 0; off >>= 1) v += __shfl_xor(v, off, 64);
  return v;
}

__device__ __forceinline__ float bf2f(unsigned short u) {
  return __builtin_bit_cast(float, (unsigned)u << 16);
}

__device__ __forceinline__ void gll16(const __hip_bfloat16* g, __hip_bfloat16* l) {
  __builtin_amdgcn_global_load_lds(
      (const __attribute__((address_space(1))) void*)g,
      (__attribute__((address_space(3))) void*)l, 16, 0, 0);
}

// ---------- generic (guarded) transpose for odd shapes: f32 [R][C] -> bf16 [C][R] ----------
struct TrArgs {
  const float* src[4];
  __hip_bfloat16* dst[4];
  int R[4];
  int C[4];
};

__global__ __launch_bounds__(256) void transp_kernel(TrArgs ta) {
  const int z = blockIdx.z;
  const int R = ta.R[z], C = ta.C[z];
  const int c0 = blockIdx.x * 32, r0 = blockIdx.y * 32;
  if (c0 >= C || r0 >= R) return;
  __shared__ float tile[32][33];
  const int tx = threadIdx.x & 31, ty = threadIdx.x >> 5;
  const float* src = ta.src[z];
  __hip_bfloat16* dst = ta.dst[z];
#pragma unroll
  for (int i = 0; i < 4; i++)
    tile[ty + i * 8][tx] = src[(size_t)(r0 + ty + i * 8) * C + c0 + tx];
  __syncthreads();
#pragma unroll
  for (int i = 0; i < 4; i++)
    dst[(size_t)(c0 + ty + i * 8) * R + r0 + tx] = __float2bfloat16(tile[tx][ty + i * 8]);
}

// ---------- fast transpose for the five 2048x2048 weights ----------
// 64x64 tile, float4 reads (16B/lane), ushort4 writes (8B/lane).
struct TrFArgs {
  const float* src[5];
  __hip_bfloat16* dst[5];
};

__global__ __launch_bounds__(256) void transp_fast(TrFArgs ta) {
  const int z = blockIdx.z;
  const float* __restrict__ src = ta.src[z];
  __hip_bfloat16* __restrict__ dst = ta.dst[z];
  const int c0 = blockIdx.x * 64, r0 = blockIdx.y * 64;
  __shared__ float tile[64][65];
  const int tx = threadIdx.x & 15;   // col quad / out-row quad
  const int ty = threadIdx.x >> 4;   // 0..15
#pragma unroll
  for (int p = 0; p < 4; p++) {
    const int r = p * 16 + ty;
    const float4 v = *(const float4*)&src[(size_t)(r0 + r) * HDIM + c0 + tx * 4];
    tile[r][tx * 4 + 0] = v.x;
    tile[r][tx * 4 + 1] = v.y;
    tile[r][tx * 4 + 2] = v.z;
    tile[r][tx * 4 + 3] = v.w;
  }
  __syncthreads();
#pragma unroll
  for (int p = 0; p < 4; p++) {
    const int cc = p * 16 + ty;   // source col = dst row
    const int rr = tx * 4;        // source row offset = dst col
    ushort4 o;
    o.x = __builtin_bit_cast(unsigned short, __float2bfloat16(tile[rr + 0][cc]));
    o.y = __builtin_bit_cast(unsigned short, __float2bfloat16(tile[rr + 1][cc]));
    o.z = __builtin_bit_cast(unsigned short, __float2bfloat16(tile[rr + 2][cc]));
    o.w = __builtin_bit_cast(unsigned short, __float2bfloat16(tile[rr + 3][cc]));
    *(ushort4*)&dst[(size_t)(c0 + cc) * HDIM + r0 + rr] = o;
  }
}

// ---------- LayerNorm (rows t and t-1) + token-shift fused ----------
__global__ __launch_bounds__(256) void ln1_kernel(const float* __restrict__ x,
                                                  const float* __restrict__ w,
                                                  const float* __restrict__ b,
                                                  const float* __restrict__ s1,
                                                  const float* __restrict__ tmx,
                                                  float* __restrict__ xl,
                                                  __hip_bfloat16* __restrict__ xxx,
                                                  float* __restrict__ s1out) {
  const int t = blockIdx.x;
  const int tid = threadIdx.x;
  const int wid = tid >> 6, lane = tid & 63;
  const float4* xr = (const float4*)(x + (size_t)t * HDIM);
  const float4* xp = (const float4*)(x + (size_t)(t > 0 ? t - 1 : 0) * HDIM);
  float4 a = xr[tid], c = xr[tid + 256];
  float4 ap = xp[tid], cp = xp[tid + 256];
  float va[8] = {a.x, a.y, a.z, a.w, c.x, c.y, c.z, c.w};
  float vp[8] = {ap.x, ap.y, ap.z, ap.w, cp.x, cp.y, cp.z, cp.w};
  float sum = 0.f, sump = 0.f;
#pragma unroll
  for (int i = 0; i < 8; i++) { sum += va[i]; sump += vp[i]; }
  sum = waveRedSum(sum);
  sump = waveRedSum(sump);
  __shared__ float red[16];
  if (lane == 0) { red[wid] = sum; red[8 + wid] = sump; }
  __syncthreads();
  const float mu = (red[0] + red[1] + red[2] + red[3]) * (1.f / HDIM);
  const float mup = (red[8] + red[9] + red[10] + red[11]) * (1.f / HDIM);
  float vs = 0.f, vsp = 0.f;
#pragma unroll
  for (int i = 0; i < 8; i++) {
    float d = va[i] - mu; vs += d * d;
    float dp = vp[i] - mup; vsp += dp * dp;
  }
  vs = waveRedSum(vs);
  vsp = waveRedSum(vsp);
  if (lane == 0) { red[4 + wid] = vs; red[12 + wid] = vsp; }
  __syncthreads();
  const float rstd = rsqrtf((red[4] + red[5] + red[6] + red[7]) * (1.f / HDIM) + 1e-5f);
  const float rstdp = rsqrtf((red[12] + red[13] + red[14] + red[15]) * (1.f / HDIM) + 1e-5f);
  float* xrow = xl + (size_t)t * HDIM;
  __hip_bfloat16* xxrow = xxx + (size_t)t * HDIM;
#pragma unroll
  for (int i = 0; i < 8; i++) {
    const int idx = (i < 4) ? (4 * tid + i) : (1024 + 4 * tid + (i - 4));
    const float wv = w[idx], bv = b[idx];
    const float cur = (va[i] - mu) * rstd * wv + bv;
    const float past = (t > 0) ? (vp[i] - mup) * rstdp * wv + bv : s1[idx];
    xrow[idx] = cur;
    xxrow[idx] = __float2bfloat16(cur + (past - cur) * tmx[idx]);
    if (t == TLEN - 1) s1out[idx] = cur;
  }
}

// ---------- mix: x5[f] = xl + sx * (t5[f] @ w2[f] + time_maa[f]) ----------
__global__ __launch_bounds__(256) void mix_kernel(const float* __restrict__ t5,
                                                  const float* __restrict__ xl,
                                                  const float* __restrict__ s1,
                                                  const float* __restrict__ w2,
                                                  const float* __restrict__ maa,
                                                  __hip_bfloat16* __restrict__ x5b) {
  const int h = blockIdx.x * 256 + threadIdx.x;
  const int t0 = blockIdx.y * 8;
  __shared__ float t5L[8 * 160];
  for (int i = threadIdx.x; i < 8 * 160; i += 256) {
    const int rr = i / 160, cc = i - rr * 160;
    t5L[i] = t5[(size_t)(t0 + rr) * 160 + cc];
  }
  __syncthreads();
  float mixv[8][5];
#pragma unroll
  for (int ts = 0; ts < 8; ts++)
#pragma unroll
    for (int f = 0; f < 5; f++) mixv[ts][f] = 0.f;
#pragma unroll
  for (int f = 0; f < 5; f++) {
#pragma unroll 4
    for (int m = 0; m < 32; m++) {
      const float w2v = w2[(size_t)(f * 32 + m) * HDIM + h];
#pragma unroll
      for (int ts = 0; ts < 8; ts++) mixv[ts][f] += t5L[ts * 160 + f * 32 + m] * w2v;
    }
  }
#pragma unroll
  for (int ts = 0; ts < 8; ts++) {
    const int t = t0 + ts;
    const float cur = xl[(size_t)t * HDIM + h];
    const float past = (t > 0) ? xl[(size_t)(t - 1) * HDIM + h] : s1[h];
    const float sx = past - cur;
#pragma unroll
    for (int f = 0; f < 5; f++) {
      const float v = cur + sx * (mixv[ts][f] + maa[(size_t)f * HDIM + h]);
      x5b[(size_t)f * THE + (size_t)t * HDIM + h] = __float2bfloat16(v);
    }
  }
}

// ---------- batched MFMA GEMM: C[z] = epi( A[z](MxK) @ Bt[z](NxK)^T ) ----------
// BK=64, double-buffered LDS, counted-vmcnt pipeline, conflict-free swizzle.
struct GemmArgs {
  const __hip_bfloat16* A[8];
  const __hip_bfloat16* B[8];
  void* C[8];
  const float* aux[8];
  int epi[8];
  int M, N, K, Ks;
};

__global__ __launch_bounds__(256) void gemm_bt(GemmArgs ga) {
  const int z = blockIdx.z;
  const __hip_bfloat16* __restrict__ A = ga.A[z];
  const __hip_bfloat16* __restrict__ Bt = ga.B[z];
  const int N = ga.N, K = ga.K, Ks = ga.Ks;
  const int epi = ga.epi[z];
  const float* __restrict__ aux = ga.aux[z];
  void* Cz = ga.C[z];

  __shared__ __align__(16) __hip_bfloat16 As[2][128 * 64];
  __shared__ __align__(16) __hip_bfloat16 Bs[2][128 * 64];

  const int tid = threadIdx.x;
  const int wid = tid >> 6;
  const int lane = tid & 63;

  int bx = blockIdx.x, by = blockIdx.y;
  if (gridDim.x == 8 && gridDim.y == 16) {
    const int flat = bx + 8 * by;
    const int xcd = flat & 7, rem = flat >> 3;
    bx = rem & 7;
    by = xcd + 8 * (rem >> 3);
  }
  const int m0 = bx * 128;
  const int n0 = by * 128;
  const int wr = wid >> 1, wc = wid & 1;

  const int srow = lane >> 3;
  const int chunkS = (lane & 7) ^ srow;
  const __hip_bfloat16* aSrcQ[4];
  const __hip_bfloat16* bSrcQ[4];
#pragma unroll
  for (int q = 0; q < 4; q++) {
    const int arow = wid * 32 + q * 8 + srow;
    int brow = n0 + arow; if (brow > N - 1) brow = N - 1;
    aSrcQ[q] = A + (size_t)(m0 + arow) * Ks + chunkS * 8;
    bSrcQ[q] = Bt + (size_t)brow * Ks + chunkS * 8;
  }

  f32x4 acc[4][4];
#pragma unroll
  for (int m = 0; m < 4; m++)
#pragma unroll
    for (int n = 0; n < 4; n++) acc[m][n] = 0.f;

  const int lr = lane & 15;
  const int cbase = lane >> 4;
  int aoffk[2], boffk[2];
#pragma unroll
  for (int kg = 0; kg < 2; kg++) {
    const int phys = (kg * 4 + cbase) ^ (lr & 7);
    aoffk[kg] = (wr * 64 + lr) * 64 + phys * 8;
    boffk[kg] = (wc * 64 + lr) * 64 + phys * 8;
  }

#define STAGE(BUF, KT)                                              \
  do {                                                              \
    _Pragma("unroll") for (int q = 0; q < 4; q++) {                 \
      gll16(aSrcQ[q] + (KT), &As[BUF][(wid * 32 + q * 8) * 64]);    \
      gll16(bSrcQ[q] + (KT), &Bs[BUF][(wid * 32 + q * 8) * 64]);    \
    }                                                               \
  } while (0)

  STAGE(0, 0);
  int cur = 0;
  for (int kt = 0; kt < K; kt += 64) {
    const bool more = (kt + 64 < K);
    if (more) {
      STAGE(cur ^ 1, kt + 64);
      asm volatile("s_waitcnt vmcnt(8)" ::: "memory");
    } else {
      asm volatile("s_waitcnt vmcnt(0)" ::: "memory");
    }
    __builtin_amdgcn_s_barrier();
#pragma unroll
    for (int kg = 0; kg < 2; kg++) {
      bf16x8 af[4], bfv[4];
#pragma unroll
      for (int m = 0; m < 4; m++) af[m] = *(const bf16x8*)&As[cur][aoffk[kg] + m * 16 * 64];
#pragma unroll
      for (int n = 0; n < 4; n++) bfv[n] = *(const bf16x8*)&Bs[cur][boffk[kg] + n * 16 * 64];
#pragma unroll
      for (int m = 0; m < 4; m++)
#pragma unroll
        for (int n = 0; n < 4; n++)
          acc[m][n] = __builtin_amdgcn_mfma_f32_16x16x32_bf16(af[m], bfv[n], acc[m][n], 0, 0, 0);
    }
    __builtin_amdgcn_s_barrier();
    cur ^= 1;
  }
#undef STAGE

  const int r4 = (lane >> 4) * 4;
#pragma unroll
  for (int m = 0; m < 4; m++) {
#pragma unroll
    for (int n = 0; n < 4; n++) {
      const int gn = n0 + wc * 64 + n * 16 + lr;
      if (gn < N) {
#pragma unroll
        for (int r = 0; r < 4; r++) {
          const int gm = m0 + wr * 64 + m * 16 + r4 + r;
          const size_t idx = (size_t)gm * N + gn;
          const float v = acc[m][n][r];
          switch (epi) {
            case 0: ((__hip_bfloat16*)Cz)[idx] = __float2bfloat16(v); break;
            case 1: ((__hip_bfloat16*)Cz)[idx] = __float2bfloat16(v / (1.f + expf(-v))); break;
            case 2: ((float*)Cz)[idx] = tanhf(v); break;
            case 3: ((__hip_bfloat16*)Cz)[idx] = __float2bfloat16(tanhf(v)); break;
            case 5: ((float*)Cz)[idx] = v + aux[idx]; break;
            case 6: ((float*)Cz)[idx] = v; break;
          }
        }
      }
    }
  }
}

// ---------- split-K combines ----------
__global__ __launch_bounds__(256) void comb8_tanh_f32(const float* __restrict__ p,
                                                      float* __restrict__ o, int n) {
  const int i = blockIdx.x * 256 + threadIdx.x;
  float s = 0.f;
#pragma unroll
  for (int k = 0; k < 8; k++) s += p[(size_t)k * n + i];
  o[i] = tanhf(s);
}

__global__ __launch_bounds__(256) void comb8_tanh_bf16(const float* __restrict__ p,
                                                       __hip_bfloat16* __restrict__ o, int n) {
  const int i = blockIdx.x * 256 + threadIdx.x;
  float s = 0.f;
#pragma unroll
  for (int k = 0; k < 8; k++) s += p[(size_t)k * n + i];
  o[i] = __float2bfloat16(tanhf(s));
}

__global__ __launch_bounds__(256) void comb4_resid(const float* __restrict__ p,
                                                   const float* __restrict__ x,
                                                   float* __restrict__ o) {
  const int i = blockIdx.x * 256 + threadIdx.x;
  const float4 a = ((const float4*)p)[i];
  const float4 b = ((const float4*)(p + THE))[i];
  const float4 c = ((const float4*)(p + 2 * (size_t)THE))[i];
  const float4 d = ((const float4*)(p + 3 * (size_t)THE))[i];
  const float4 e = ((const float4*)x)[i];
  ((float4*)o)[i] = make_float4(a.x + b.x + c.x + d.x + e.x,
                                a.y + b.y + c.y + d.y + e.y,
                                a.z + b.z + c.z + d.z + e.z,
                                a.w + b.w + c.w + d.w + e.w);
}

// ---------- td = exp(-exp(clip(tw @ dw2 + dp)))  -- K=64 dot, memory-bound ----------
__global__ __launch_bounds__(256) void tdcalc_kernel(const __hip_bfloat16* __restrict__ tw,
                                                     const __hip_bfloat16* __restrict__ dw2t,
                                                     const float* __restrict__ dp,
                                                     float* __restrict__ td) {
  const int t0 = blockIdx.x * 4;
  const int n = blockIdx.y * 256 + threadIdx.x;
  __shared__ float twL[4][64];
  {
    const int row = threadIdx.x >> 6, col = threadIdx.x & 63;
    twL[row][col] = __bfloat162float(tw[(size_t)(t0 + row) * 64 + col]);
  }
  __syncthreads();
  float acc[4] = {0.f, 0.f, 0.f, 0.f};
  const bf16x8* drow = (const bf16x8*)(dw2t + (size_t)n * 64);
#pragma unroll
  for (int ch = 0; ch < 8; ch++) {
    const bf16x8 v = drow[ch];
#pragma unroll
    for (int e = 0; e < 8; e++) {
      const float b = bf2f((unsigned short)v[e]);
      const int col = ch * 8 + e;
#pragma unroll
      for (int r = 0; r < 4; r++) acc[r] = fmaf(twL[r][col], b, acc[r]);
    }
  }
  const float dpn = dp[n];
#pragma unroll
  for (int r = 0; r < 4; r++) {
    float wv = acc[r] + dpn;
    wv = fminf(fmaxf(wv, -9.72f), 2.27f);
    td[(size_t)(t0 + r) * HDIM + n] = expf(-expf(wv));
  }
}

// ---------- single local scan pass (+ fused decay: rt, Ptot) ----------
__global__ __launch_bounds__(256) void scan_local_kernel(const __hip_bfloat16* __restrict__ kb,
                                                         const __hip_bfloat16* __restrict__ rb,
                                                         const float* __restrict__ td,
                                                         const __hip_bfloat16* __restrict__ vb,
                                                         float* __restrict__ wkv,
                                                         float* __restrict__ qT,
                                                         __hip_bfloat16* __restrict__ rt,
                                                         float* __restrict__ Ptot) {
  const int blk = blockIdx.x;           // c*NHEAD + h
  const int c = blk >> 5, h = blk & 31;
  const int w = threadIdx.x >> 6;       // j-quarter 0..3
  const int i = threadIdx.x & 63;       // lane = output row
  __shared__ float plds[2][4][64];

  float s[16];
#pragma unroll
  for (int q = 0; q < 16; q++) s[q] = 0.f;

  const int t0 = c * CT;
  const int hb = h * HSZ;
  const int jSelf = w * 16 + (i & 15);  // this thread's decay-tracked column
  float Aself = 1.f;
  __hip_bfloat16* rtbase = rt + (((size_t)c * NHEAD + h) * CT) * HSZ + jSelf;

  for (int t = 0; t < CT; t++) {
    const size_t rowb = (size_t)(t0 + t) * HDIM + hb;
    const unsigned* kw = (const unsigned*)(kb + rowb + w * 16);  // 8 dwords (uniform)
    const unsigned* rw = (const unsigned*)(rb + rowb + w * 16);
    const float* tdw = td + rowb + w * 16;
    const float vi = __bfloat162float(vb[rowb + i]);
    float p = 0.f;
#pragma unroll
    for (int m = 0; m < 8; m++) {
      const unsigned kpair = kw[m];
      const unsigned rpair = rw[m];
      const float k0 = __builtin_bit_cast(float, kpair << 16);
      const float k1 = __builtin_bit_cast(float, kpair & 0xffff0000u);
      const float r0 = __builtin_bit_cast(float, rpair << 16);
      const float r1 = __builtin_bit_cast(float, rpair & 0xffff0000u);
      const float td0 = tdw[2 * m];
      const float td1 = tdw[2 * m + 1];
      const float kv0 = vi * k0;
      const float kv1 = vi * k1;
      p = fmaf(r0, s[2 * m], p);
      p = fmaf(r1, s[2 * m + 1], p);
      s[2 * m] = fmaf(s[2 * m], td0, kv0);
      s[2 * m + 1] = fmaf(s[2 * m + 1], td1, kv1);
    }
    // fused decay: rt[t][jSelf] = r * cumA(t-1); A *= td
    const float rself = __bfloat162float(rb[rowb + jSelf]);
    if (i < 16) rtbase[(size_t)t * HSZ] = __float2bfloat16(rself * Aself);
    Aself *= td[rowb + jSelf];

    plds[t & 1][w][i] = p;
    __syncthreads();
    if (w == 0) {
      wkv[rowb + i] = plds[t & 1][0][i] + plds[t & 1][1][i] +
                      plds[t & 1][2][i] + plds[t & 1][3][i];
    }
  }
  if (i < 16) Ptot[((size_t)c * NHEAD + h) * HSZ + jSelf] = Aself;
  float* qbase = qT + (((size_t)c * NHEAD + h) * HSZ + w * 16) * HSZ + i;
#pragma unroll
  for (int q = 0; q < 16; q++) qbase[(size_t)q * HSZ] = s[q];
}

// ---------- sequential chunk combine: s0b (bf16) per chunk + s2out ----------
__global__ __launch_bounds__(64) void scan_s_kernel(const float* __restrict__ qT,
                                                    const float* __restrict__ Ptot,
                                                    const float* __restrict__ s2in,
                                                    __hip_bfloat16* __restrict__ s0b,
                                                    float* __restrict__ s2out) {
  const int h = blockIdx.x, i = blockIdx.y, j = threadIdx.x;
  float s = s2in[((size_t)h * HSZ + i) * HSZ + j];
#pragma unroll 4
  for (int c = 0; c < NC; c++) {
    s0b[(((size_t)c * NHEAD + h) * HSZ + i) * HSZ + j] = __float2bfloat16(s);
    s = fmaf(s, Ptot[((size_t)c * NHEAD + h) * HSZ + j],
             qT[(((size_t)c * NHEAD + h) * HSZ + j) * HSZ + i]);
  }
  s2out[((size_t)h * HSZ + i) * HSZ + j] = s;
}

// ---------- correction GEMM: wkv[c*CT+t][h][i] += sum_j rt[t][j] * s0b[i][j] ----------
__global__ __launch_bounds__(256) void corr_kernel(const __hip_bfloat16* __restrict__ rt,
                                                   const __hip_bfloat16* __restrict__ s0b,
                                                   float* __restrict__ wkv) {
  const int c = blockIdx.x, h = blockIdx.y;
  const int w = threadIdx.x >> 6;   // n-tile (i)
  const int lane = threadIdx.x & 63;
  const int lr = lane & 15, lk = (lane >> 4) * 8;
  const __hip_bfloat16* rbase = rt + (((size_t)c * NHEAD + h) * CT) * HSZ;
  const __hip_bfloat16* sbase = s0b + (((size_t)c * NHEAD + h) * HSZ) * HSZ;
  float* wbase = wkv + (size_t)(c * CT) * HDIM + h * HSZ;
#pragma unroll
  for (int mt = 0; mt < CT / 16; mt++) {
    f32x4 acc = {0.f, 0.f, 0.f, 0.f};
#pragma unroll
    for (int ks = 0; ks < 2; ks++) {
      bf16x8 af = *(const bf16x8*)(rbase + (size_t)(mt * 16 + lr) * HSZ + ks * 32 + lk);
      bf16x8 bf = *(const bf16x8*)(sbase + (size_t)(w * 16 + lr) * HSZ + ks * 32 + lk);
      acc = __builtin_amdgcn_mfma_f32_16x16x32_bf16(af, bf, acc, 0, 0, 0);
    }
    const int row = mt * 16 + (lane >> 4) * 4;
    const int col = w * 16 + lr;
#pragma unroll
    for (int r = 0; r < 4; r++)
      wbase[(size_t)(row + r) * HDIM + col] += acc[r];
  }
}

// ---------- group norm over HS (+diag wkv term) + scale/bias + gate ----------
__global__ __launch_bounds__(256) void gnorm_kernel(const float* __restrict__ wkv,
                                                    const __hip_bfloat16* __restrict__ kb,
                                                    const __hip_bfloat16* __restrict__ rb,
                                                    const float* __restrict__ tf,
                                                    const __hip_bfloat16* __restrict__ vb,
                                                    const __hip_bfloat16* __restrict__ gb,
                                                    const float* __restrict__ lnw,
                                                    const float* __restrict__ lnb,
                                                    __hip_bfloat16* __restrict__ yA) {
  const int t = blockIdx.x;
  const int wid = threadIdx.x >> 6, j = threadIdx.x & 63;
  const int h = blockIdx.y * 4 + wid;
  const size_t idx = (size_t)t * HDIM + h * HSZ + j;
  const float kj = __bfloat162float(kb[idx]);
  const float rj = __bfloat162float(rb[idx]);
  const float dg = waveRedSum(rj * tf[h * HSZ + j] * kj);
  const float v = wkv[idx] + dg * __bfloat162float(vb[idx]);
  const float mu = waveRedSum(v) * (1.f / HSZ);
  const float d = v - mu;
  const float var = waveRedSum(d * d) * (1.f / HSZ);
  float y = d * rsqrtf(var + 1e-5f);
  y = y * lnw[h * HSZ + j] + lnb[h * HSZ + j];
  y *= __bfloat162float(gb[idx]);
  yA[idx] = __float2bfloat16(y);
}

extern "C" void kernel_launch(void* const* d_in, const int* in_sizes, int n_in,
                              void* d_out, int out_size, void* d_ws, size_t ws_size,
                              hipStream_t stream) {
  (void)in_sizes; (void)n_in; (void)out_size; (void)ws_size;

  const float* x    = (const float*)d_in[0];
  const float* s1   = (const float*)d_in[1];
  const float* s2   = (const float*)d_in[2];
  const float* ln1w = (const float*)d_in[3];
  const float* ln1b = (const float*)d_in[4];
  const float* tmx  = (const float*)d_in[5];
  const float* tmaa = (const float*)d_in[6];
  const float* w1   = (const float*)d_in[7];
  const float* w2   = (const float*)d_in[8];
  const float* dw1  = (const float*)d_in[9];
  const float* dw2  = (const float*)d_in[10];
  const float* dp   = (const float*)d_in[11];
  const float* tf   = (const float*)d_in[12];
  const float* Wr   = (const float*)d_in[13];
  const float* Wk   = (const float*)d_in[14];
  const float* Wv   = (const float*)d_in[15];
  const float* Wg   = (const float*)d_in[16];
  const float* Wo   = (const float*)d_in[17];
  const float* lnxw = (const float*)d_in[18];
  const float* lnxb = (const float*)d_in[19];

  float* out0  = (float*)d_out;
  float* s1out = out0 + (size_t)TLEN * HDIM;
  float* s2out = s1out + HDIM;

  char* wp = (char*)d_ws;
  size_t off = 0;
  auto carve = [&](size_t bytes) -> void* {
    void* r = wp + off;
    off += (bytes + 255) & ~(size_t)255;
    return r;
  };

  __hip_bfloat16* wrt  = (__hip_bfloat16*)carve((size_t)HDIM * HDIM * 2);
  __hip_bfloat16* wkt  = (__hip_bfloat16*)carve((size_t)HDIM * HDIM * 2);
  __hip_bfloat16* wvt  = (__hip_bfloat16*)carve((size_t)HDIM * HDIM * 2);
  __hip_bfloat16* wgt  = (__hip_bfloat16*)carve((size_t)HDIM * HDIM * 2);
  __hip_bfloat16* wot  = (__hip_bfloat16*)carve((size_t)HDIM * HDIM * 2);
  __hip_bfloat16* w1t  = (__hip_bfloat16*)carve((size_t)160 * HDIM * 2);
  __hip_bfloat16* dw1t = (__hip_bfloat16*)carve((size_t)64 * HDIM * 2);
  __hip_bfloat16* dw2t = (__hip_bfloat16*)carve((size_t)HDIM * 64 * 2);
  float* xl            = (float*)carve((size_t)THE * 4);
  __hip_bfloat16* xxx  = (__hip_bfloat16*)carve((size_t)THE * 2);
  float* t5            = (float*)carve((size_t)TLEN * 160 * 4);
  __hip_bfloat16* x5b  = (__hip_bfloat16*)carve((size_t)5 * THE * 2);
  __hip_bfloat16* rb   = (__hip_bfloat16*)carve((size_t)THE * 2);
  __hip_bfloat16* kb   = (__hip_bfloat16*)carve((size_t)THE * 2);
  __hip_bfloat16* vb   = (__hip_bfloat16*)carve((size_t)THE * 2);
  __hip_bfloat16* gb   = (__hip_bfloat16*)carve((size_t)THE * 2);
  __hip_bfloat16* tw   = (__hip_bfloat16*)carve((size_t)TLEN * 64 * 2);
  float* td            = (float*)carve((size_t)THE * 4);
  float* wkv           = (float*)carve((size_t)THE * 4);
  __hip_bfloat16* yA   = (__hip_bfloat16*)carve((size_t)THE * 2);

  // Aliased scratch (all regions dead at time of use) -- unchanged from r14.
  float* qT            = (float*)x5b;
  __hip_bfloat16* rt   = (__hip_bfloat16*)xl;
  __hip_bfloat16* s0b  = (__hip_bfloat16*)td;
  float* Ptot          = (float*)t5;
  float* pg1           = (float*)td;
  float* pg4           = (float*)xxx;
  float* pg6           = (float*)x5b;

  // K0a: fast transpose for the five 2048x2048 weights (float4/ushort4)
  {
    TrFArgs tf5;
    const float* s5[5] = {Wr, Wk, Wv, Wg, Wo};
    __hip_bfloat16* d5[5] = {wrt, wkt, wvt, wgt, wot};
    for (int z = 0; z < 5; z++) { tf5.src[z] = s5[z]; tf5.dst[z] = d5[z]; }
    transp_fast<<<dim3(HDIM / 64, HDIM / 64, 5), 256, 0, stream>>>(tf5);
  }
  // K0b: guarded transpose for the odd-shaped small weights
  {
    TrArgs ta;
    const float* s3[3] = {w1, dw1, dw2};
    __hip_bfloat16* d3[3] = {w1t, dw1t, dw2t};
    const int Rs[3] = {HDIM, HDIM, 64};
    const int Cs[3] = {160, 64, HDIM};
    for (int z = 0; z < 3; z++) { ta.src[z] = s3[z]; ta.dst[z] = d3[z]; ta.R[z] = Rs[z]; ta.C[z] = Cs[z]; }
    transp_kernel<<<dim3(64, 64, 3), 256, 0, stream>>>(ta);
  }

  // K1: layernorm + token-shift fused -> xl, xxx
  ln1_kernel<<<dim3(TLEN), 256, 0, stream>>>(x, ln1w, ln1b, s1, tmx, xl, xxx, s1out);

  // G1: t5 = tanh(xxx @ w1)  (M=1024, N=160, K=2048) -- split-K=8
  {
    GemmArgs g{};
    for (int ks = 0; ks < 8; ks++) {
      g.A[ks] = xxx + ks * 256;
      g.B[ks] = w1t + ks * 256;
      g.C[ks] = pg1 + (size_t)ks * TLEN * 160;
      g.epi[ks] = 6;
    }
    g.M = TLEN; g.N = 160; g.K = 256; g.Ks = HDIM;
    gemm_bt<<<dim3(TLEN / 128, 2, 8), 256, 0, stream>>>(g);
    comb8_tanh_f32<<<dim3(TLEN * 160 / 256), 256, 0, stream>>>(pg1, t5, TLEN * 160);
  }

  // K4: mix + x5 (5 planes, bf16)
  mix_kernel<<<dim3(HDIM / 256, TLEN / 8), 256, 0, stream>>>(t5, xl, s1, w2, tmaa, x5b);

  // G2: r, k, v, g  (batched z=4)
  {
    GemmArgs g{};
    g.A[0] = x5b + (size_t)3 * THE; g.B[0] = wrt; g.C[0] = rb; g.epi[0] = 0;
    g.A[1] = x5b + (size_t)1 * THE; g.B[1] = wkt; g.C[1] = kb; g.epi[1] = 0;
    g.A[2] = x5b + (size_t)2 * THE; g.B[2] = wvt; g.C[2] = vb; g.epi[2] = 0;
    g.A[3] = x5b + (size_t)4 * THE; g.B[3] = wgt; g.C[3] = gb; g.epi[3] = 1;
    g.M = TLEN; g.N = HDIM; g.K = HDIM; g.Ks = HDIM;
    gemm_bt<<<dim3(TLEN / 128, HDIM / 128, 4), 256, 0, stream>>>(g);
  }

  // G4: tw = tanh(mw @ dw1)  (N=64) -- split-K=8
  {
    GemmArgs g{};
    for (int ks = 0; ks < 8; ks++) {
      g.A[ks] = x5b + ks * 256;          // plane 0 = mw
      g.B[ks] = dw1t + ks * 256;
      g.C[ks] = pg4 + (size_t)ks * TLEN * 64;
      g.epi[ks] = 6;
    }
    g.M = TLEN; g.N = 64; g.K = 256; g.Ks = HDIM;
    gemm_bt<<<dim3(TLEN / 128, 1, 8), 256, 0, stream>>>(g);
    comb8_tanh_bf16<<<dim3(TLEN * 64 / 256), 256, 0, stream>>>(pg4, tw, TLEN * 64);
  }

  // G5': td = exp(-exp(clip(tw @ dw2 + p))) -- dedicated memory-bound kernel
  tdcalc_kernel<<<dim3(TLEN / 4, HDIM / 256), 256, 0, stream>>>(tw, dw2t, dp, td);

  // Scan stage: local pass (+decay fused), chunk combine, MFMA correction
  scan_local_kernel<<<dim3(NC * NHEAD), 256, 0, stream>>>(kb, rb, td, vb, wkv, qT, rt, Ptot);
  scan_s_kernel<<<dim3(NHEAD, HSZ), 64, 0, stream>>>(qT, Ptot, s2, s0b, s2out);
  corr_kernel<<<dim3(NC, NHEAD), 256, 0, stream>>>(rt, s0b, wkv);

  // K7: group-norm (+diag term) + gate -> yA (bf16)
  gnorm_kernel<<<dim3(TLEN, NHEAD / 4), 256, 0, stream>>>(wkv, kb, rb, tf, vb, gb, lnxw, lnxb, yA);

  // G6: out = x + yA @ W_o  -- split-K=4 (512 blocks = 2 blocks/CU TLP threshold)
  {
    GemmArgs g{};
    for (int ks = 0; ks < 4; ks++) {
      g.A[ks] = yA + ks * 512;
      g.B[ks] = wot + ks * 512;
      g.C[ks] = pg6 + (size_t)ks * THE;
      g.epi[ks] = 6;
    }
    g.M = TLEN; g.N = HDIM; g.K = 512; g.Ks = HDIM;
    gemm_bt<<<dim3(TLEN / 128, HDIM / 128, 4), 256, 0, stream>>>(g);
    comb4_resid<<<dim3(THE / 4 / 256), 256, 0, stream>>>(pg6, x, out0);
  }
}

// Round 16
// 270.570 us; speedup vs baseline: 1.1565x; 1.0013x over previous
//
#include <hip/hip_runtime.h>
#include <hip/hip_bf16.h>
#include <math.h>

#define TLEN 1024
#define HDIM 2048
#define NHEAD 32
#define HSZ 64
#define THE (TLEN * HDIM)
#define NC 32          // scan chunks
#define CT (TLEN / NC) // 32 timesteps per chunk

typedef __attribute__((ext_vector_type(8))) short bf16x8;
typedef __attribute__((ext_vector_type(4))) float f32x4;

__device__ __forceinline__ float waveRedSum(float v) {
#pragma unroll
  for (int off = 32; off > 0; off >>= 1) v += __shfl_xor(v, off, 64);
  return v;
}

__device__ __forceinline__ float bf2f(unsigned short u) {
  return __builtin_bit_cast(float, (unsigned)u << 16);
}

__device__ __forceinline__ void gll16(const __hip_bfloat16* g, __hip_bfloat16* l) {
  __builtin_amdgcn_global_load_lds(
      (const __attribute__((address_space(1))) void*)g,
      (__attribute__((address_space(3))) void*)l, 16, 0, 0);
}

// ---------- unified transpose: z<5 fast 64x64 (2048x2048), z>=5 guarded 32x32 ----------
struct TrAllArgs {
  const float* src[8];
  __hip_bfloat16* dst[8];
  int R[8];
  int C[8];
};

__global__ __launch_bounds__(256) void transp_all(TrAllArgs ta) {
  const int z = blockIdx.z;
  const float* __restrict__ src = ta.src[z];
  __hip_bfloat16* __restrict__ dst = ta.dst[z];
  if (z < 5) {
    // fast path: 2048x2048, 64x64 tile, float4 reads / ushort4 writes
    if (blockIdx.x >= 32 || blockIdx.y >= 32) return;
    const int c0 = blockIdx.x * 64, r0 = blockIdx.y * 64;
    __shared__ float tile[64][65];
    const int tx = threadIdx.x & 15;
    const int ty = threadIdx.x >> 4;
#pragma unroll
    for (int p = 0; p < 4; p++) {
      const int r = p * 16 + ty;
      const float4 v = *(const float4*)&src[(size_t)(r0 + r) * HDIM + c0 + tx * 4];
      tile[r][tx * 4 + 0] = v.x;
      tile[r][tx * 4 + 1] = v.y;
      tile[r][tx * 4 + 2] = v.z;
      tile[r][tx * 4 + 3] = v.w;
    }
    __syncthreads();
#pragma unroll
    for (int p = 0; p < 4; p++) {
      const int cc = p * 16 + ty;
      const int rr = tx * 4;
      ushort4 o;
      o.x = __builtin_bit_cast(unsigned short, __float2bfloat16(tile[rr + 0][cc]));
      o.y = __builtin_bit_cast(unsigned short, __float2bfloat16(tile[rr + 1][cc]));
      o.z = __builtin_bit_cast(unsigned short, __float2bfloat16(tile[rr + 2][cc]));
      o.w = __builtin_bit_cast(unsigned short, __float2bfloat16(tile[rr + 3][cc]));
      *(ushort4*)&dst[(size_t)(c0 + cc) * HDIM + r0 + rr] = o;
    }
  } else {
    const int R = ta.R[z], C = ta.C[z];
    const int c0 = blockIdx.x * 32, r0 = blockIdx.y * 32;
    if (c0 >= C || r0 >= R) return;
    __shared__ float tile[32][33];
    const int tx = threadIdx.x & 31, ty = threadIdx.x >> 5;
#pragma unroll
    for (int i = 0; i < 4; i++)
      tile[ty + i * 8][tx] = src[(size_t)(r0 + ty + i * 8) * C + c0 + tx];
    __syncthreads();
#pragma unroll
    for (int i = 0; i < 4; i++)
      dst[(size_t)(c0 + ty + i * 8) * R + r0 + tx] = __float2bfloat16(tile[tx][ty + i * 8]);
  }
}

// ---------- LayerNorm (rows t and t-1) + token-shift fused ----------
__global__ __launch_bounds__(256) void ln1_kernel(const float* __restrict__ x,
                                                  const float* __restrict__ w,
                                                  const float* __restrict__ b,
                                                  const float* __restrict__ s1,
                                                  const float* __restrict__ tmx,
                                                  float* __restrict__ xl,
                                                  __hip_bfloat16* __restrict__ xxx,
                                                  float* __restrict__ s1out) {
  const int t = blockIdx.x;
  const int tid = threadIdx.x;
  const int wid = tid >> 6, lane = tid & 63;
  const float4* xr = (const float4*)(x + (size_t)t * HDIM);
  const float4* xp = (const float4*)(x + (size_t)(t > 0 ? t - 1 : 0) * HDIM);
  float4 a = xr[tid], c = xr[tid + 256];
  float4 ap = xp[tid], cp = xp[tid + 256];
  float va[8] = {a.x, a.y, a.z, a.w, c.x, c.y, c.z, c.w};
  float vp[8] = {ap.x, ap.y, ap.z, ap.w, cp.x, cp.y, cp.z, cp.w};
  float sum = 0.f, sump = 0.f;
#pragma unroll
  for (int i = 0; i < 8; i++) { sum += va[i]; sump += vp[i]; }
  sum = waveRedSum(sum);
  sump = waveRedSum(sump);
  __shared__ float red[16];
  if (lane == 0) { red[wid] = sum; red[8 + wid] = sump; }
  __syncthreads();
  const float mu = (red[0] + red[1] + red[2] + red[3]) * (1.f / HDIM);
  const float mup = (red[8] + red[9] + red[10] + red[11]) * (1.f / HDIM);
  float vs = 0.f, vsp = 0.f;
#pragma unroll
  for (int i = 0; i < 8; i++) {
    float d = va[i] - mu; vs += d * d;
    float dp = vp[i] - mup; vsp += dp * dp;
  }
  vs = waveRedSum(vs);
  vsp = waveRedSum(vsp);
  if (lane == 0) { red[4 + wid] = vs; red[12 + wid] = vsp; }
  __syncthreads();
  const float rstd = rsqrtf((red[4] + red[5] + red[6] + red[7]) * (1.f / HDIM) + 1e-5f);
  const float rstdp = rsqrtf((red[12] + red[13] + red[14] + red[15]) * (1.f / HDIM) + 1e-5f);
  float* xrow = xl + (size_t)t * HDIM;
  __hip_bfloat16* xxrow = xxx + (size_t)t * HDIM;
#pragma unroll
  for (int i = 0; i < 8; i++) {
    const int idx = (i < 4) ? (4 * tid + i) : (1024 + 4 * tid + (i - 4));
    const float wv = w[idx], bv = b[idx];
    const float cur = (va[i] - mu) * rstd * wv + bv;
    const float past = (t > 0) ? (vp[i] - mup) * rstdp * wv + bv : s1[idx];
    xrow[idx] = cur;
    xxrow[idx] = __float2bfloat16(cur + (past - cur) * tmx[idx]);
    if (t == TLEN - 1) s1out[idx] = cur;
  }
}

// ---------- mix (+ fused G1 combine: t5 = tanh(sum of 8 partials)) ----------
__global__ __launch_bounds__(256) void mix_kernel(const float* __restrict__ pg1,
                                                  const float* __restrict__ xl,
                                                  const float* __restrict__ s1,
                                                  const float* __restrict__ w2,
                                                  const float* __restrict__ maa,
                                                  __hip_bfloat16* __restrict__ x5b) {
  const int h = blockIdx.x * 256 + threadIdx.x;
  const int t0 = blockIdx.y * 8;
  __shared__ float t5L[8 * 160];
  for (int i = threadIdx.x; i < 8 * 160; i += 256) {
    const int rr = i / 160, cc = i - rr * 160;
    const size_t base = (size_t)(t0 + rr) * 160 + cc;
    float s = 0.f;
#pragma unroll
    for (int k = 0; k < 8; k++) s += pg1[(size_t)k * TLEN * 160 + base];
    t5L[i] = tanhf(s);
  }
  __syncthreads();
  float mixv[8][5];
#pragma unroll
  for (int ts = 0; ts < 8; ts++)
#pragma unroll
    for (int f = 0; f < 5; f++) mixv[ts][f] = 0.f;
#pragma unroll
  for (int f = 0; f < 5; f++) {
#pragma unroll 4
    for (int m = 0; m < 32; m++) {
      const float w2v = w2[(size_t)(f * 32 + m) * HDIM + h];
#pragma unroll
      for (int ts = 0; ts < 8; ts++) mixv[ts][f] += t5L[ts * 160 + f * 32 + m] * w2v;
    }
  }
#pragma unroll
  for (int ts = 0; ts < 8; ts++) {
    const int t = t0 + ts;
    const float cur = xl[(size_t)t * HDIM + h];
    const float past = (t > 0) ? xl[(size_t)(t - 1) * HDIM + h] : s1[h];
    const float sx = past - cur;
#pragma unroll
    for (int f = 0; f < 5; f++) {
      const float v = cur + sx * (mixv[ts][f] + maa[(size_t)f * HDIM + h]);
      x5b[(size_t)f * THE + (size_t)t * HDIM + h] = __float2bfloat16(v);
    }
  }
}

// ---------- batched MFMA GEMM: C[z] = epi( A[z](MxK) @ Bt[z](NxK)^T ) ----------
// BK=64, double-buffered LDS, counted-vmcnt pipeline, conflict-free swizzle.
struct GemmArgs {
  const __hip_bfloat16* A[8];
  const __hip_bfloat16* B[8];
  void* C[8];
  const float* aux[8];
  int epi[8];
  int M, N, K, Ks;
};

__global__ __launch_bounds__(256) void gemm_bt(GemmArgs ga) {
  const int z = blockIdx.z;
  const __hip_bfloat16* __restrict__ A = ga.A[z];
  const __hip_bfloat16* __restrict__ Bt = ga.B[z];
  const int N = ga.N, K = ga.K, Ks = ga.Ks;
  const int epi = ga.epi[z];
  const float* __restrict__ aux = ga.aux[z];
  void* Cz = ga.C[z];

  __shared__ __align__(16) __hip_bfloat16 As[2][128 * 64];
  __shared__ __align__(16) __hip_bfloat16 Bs[2][128 * 64];

  const int tid = threadIdx.x;
  const int wid = tid >> 6;
  const int lane = tid & 63;

  int bx = blockIdx.x, by = blockIdx.y;
  if (gridDim.x == 8 && gridDim.y == 16) {
    const int flat = bx + 8 * by;
    const int xcd = flat & 7, rem = flat >> 3;
    bx = rem & 7;
    by = xcd + 8 * (rem >> 3);
  }
  const int m0 = bx * 128;
  const int n0 = by * 128;
  const int wr = wid >> 1, wc = wid & 1;

  const int srow = lane >> 3;
  const int chunkS = (lane & 7) ^ srow;
  const __hip_bfloat16* aSrcQ[4];
  const __hip_bfloat16* bSrcQ[4];
#pragma unroll
  for (int q = 0; q < 4; q++) {
    const int arow = wid * 32 + q * 8 + srow;
    int brow = n0 + arow; if (brow > N - 1) brow = N - 1;
    aSrcQ[q] = A + (size_t)(m0 + arow) * Ks + chunkS * 8;
    bSrcQ[q] = Bt + (size_t)brow * Ks + chunkS * 8;
  }

  f32x4 acc[4][4];
#pragma unroll
  for (int m = 0; m < 4; m++)
#pragma unroll
    for (int n = 0; n < 4; n++) acc[m][n] = 0.f;

  const int lr = lane & 15;
  const int cbase = lane >> 4;
  int aoffk[2], boffk[2];
#pragma unroll
  for (int kg = 0; kg < 2; kg++) {
    const int phys = (kg * 4 + cbase) ^ (lr & 7);
    aoffk[kg] = (wr * 64 + lr) * 64 + phys * 8;
    boffk[kg] = (wc * 64 + lr) * 64 + phys * 8;
  }

#define STAGE(BUF, KT)                                              \
  do {                                                              \
    _Pragma("unroll") for (int q = 0; q < 4; q++) {                 \
      gll16(aSrcQ[q] + (KT), &As[BUF][(wid * 32 + q * 8) * 64]);    \
      gll16(bSrcQ[q] + (KT), &Bs[BUF][(wid * 32 + q * 8) * 64]);    \
    }                                                               \
  } while (0)

  STAGE(0, 0);
  int cur = 0;
  for (int kt = 0; kt < K; kt += 64) {
    const bool more = (kt + 64 < K);
    if (more) {
      STAGE(cur ^ 1, kt + 64);
      asm volatile("s_waitcnt vmcnt(8)" ::: "memory");
    } else {
      asm volatile("s_waitcnt vmcnt(0)" ::: "memory");
    }
    __builtin_amdgcn_s_barrier();
#pragma unroll
    for (int kg = 0; kg < 2; kg++) {
      bf16x8 af[4], bfv[4];
#pragma unroll
      for (int m = 0; m < 4; m++) af[m] = *(const bf16x8*)&As[cur][aoffk[kg] + m * 16 * 64];
#pragma unroll
      for (int n = 0; n < 4; n++) bfv[n] = *(const bf16x8*)&Bs[cur][boffk[kg] + n * 16 * 64];
#pragma unroll
      for (int m = 0; m < 4; m++)
#pragma unroll
        for (int n = 0; n < 4; n++)
          acc[m][n] = __builtin_amdgcn_mfma_f32_16x16x32_bf16(af[m], bfv[n], acc[m][n], 0, 0, 0);
    }
    __builtin_amdgcn_s_barrier();
    cur ^= 1;
  }
#undef STAGE

  const int r4 = (lane >> 4) * 4;
#pragma unroll
  for (int m = 0; m < 4; m++) {
#pragma unroll
    for (int n = 0; n < 4; n++) {
      const int gn = n0 + wc * 64 + n * 16 + lr;
      if (gn < N) {
#pragma unroll
        for (int r = 0; r < 4; r++) {
          const int gm = m0 + wr * 64 + m * 16 + r4 + r;
          const size_t idx = (size_t)gm * N + gn;
          const float v = acc[m][n][r];
          switch (epi) {
            case 0: ((__hip_bfloat16*)Cz)[idx] = __float2bfloat16(v); break;
            case 1: ((__hip_bfloat16*)Cz)[idx] = __float2bfloat16(v / (1.f + expf(-v))); break;
            case 2: ((float*)Cz)[idx] = tanhf(v); break;
            case 3: ((__hip_bfloat16*)Cz)[idx] = __float2bfloat16(tanhf(v)); break;
            case 5: ((float*)Cz)[idx] = v + aux[idx]; break;
            case 6: ((float*)Cz)[idx] = v; break;
          }
        }
      }
    }
  }
}

// ---------- split-K combine for G6 ----------
__global__ __launch_bounds__(256) void comb4_resid(const float* __restrict__ p,
                                                   const float* __restrict__ x,
                                                   float* __restrict__ o) {
  const int i = blockIdx.x * 256 + threadIdx.x;
  const float4 a = ((const float4*)p)[i];
  const float4 b = ((const float4*)(p + THE))[i];
  const float4 c = ((const float4*)(p + 2 * (size_t)THE))[i];
  const float4 d = ((const float4*)(p + 3 * (size_t)THE))[i];
  const float4 e = ((const float4*)x)[i];
  ((float4*)o)[i] = make_float4(a.x + b.x + c.x + d.x + e.x,
                                a.y + b.y + c.y + d.y + e.y,
                                a.z + b.z + c.z + d.z + e.z,
                                a.w + b.w + c.w + d.w + e.w);
}

// ---------- td = exp(-exp(clip(tanh(sum pg4) @ dw2 + dp))) -- fused G4-combine ----------
__global__ __launch_bounds__(256) void tdcalc_kernel(const float* __restrict__ pg4,
                                                     const __hip_bfloat16* __restrict__ dw2t,
                                                     const float* __restrict__ dp,
                                                     float* __restrict__ td) {
  const int t0 = blockIdx.x * 4;
  const int n = blockIdx.y * 256 + threadIdx.x;
  __shared__ float twL[4][64];
  {
    const int row = threadIdx.x >> 6, col = threadIdx.x & 63;
    const size_t base = (size_t)(t0 + row) * 64 + col;
    float s = 0.f;
#pragma unroll
    for (int k = 0; k < 8; k++) s += pg4[(size_t)k * TLEN * 64 + base];
    twL[row][col] = tanhf(s);
  }
  __syncthreads();
  float acc[4] = {0.f, 0.f, 0.f, 0.f};
  const bf16x8* drow = (const bf16x8*)(dw2t + (size_t)n * 64);
#pragma unroll
  for (int ch = 0; ch < 8; ch++) {
    const bf16x8 v = drow[ch];
#pragma unroll
    for (int e = 0; e < 8; e++) {
      const float b = bf2f((unsigned short)v[e]);
      const int col = ch * 8 + e;
#pragma unroll
      for (int r = 0; r < 4; r++) acc[r] = fmaf(twL[r][col], b, acc[r]);
    }
  }
  const float dpn = dp[n];
#pragma unroll
  for (int r = 0; r < 4; r++) {
    float wv = acc[r] + dpn;
    wv = fminf(fmaxf(wv, -9.72f), 2.27f);
    td[(size_t)(t0 + r) * HDIM + n] = expf(-expf(wv));
  }
}

// ---------- single local scan pass (+ fused decay: rt, Ptot) ----------
__global__ __launch_bounds__(256) void scan_local_kernel(const __hip_bfloat16* __restrict__ kb,
                                                         const __hip_bfloat16* __restrict__ rb,
                                                         const float* __restrict__ td,
                                                         const __hip_bfloat16* __restrict__ vb,
                                                         float* __restrict__ wkv,
                                                         float* __restrict__ qT,
                                                         __hip_bfloat16* __restrict__ rt,
                                                         float* __restrict__ Ptot) {
  const int blk = blockIdx.x;           // c*NHEAD + h
  const int c = blk >> 5, h = blk & 31;
  const int w = threadIdx.x >> 6;       // j-quarter 0..3
  const int i = threadIdx.x & 63;       // lane = output row
  __shared__ float plds[2][4][64];

  float s[16];
#pragma unroll
  for (int q = 0; q < 16; q++) s[q] = 0.f;

  const int t0 = c * CT;
  const int hb = h * HSZ;
  const int jSelf = w * 16 + (i & 15);
  float Aself = 1.f;
  __hip_bfloat16* rtbase = rt + (((size_t)c * NHEAD + h) * CT) * HSZ + jSelf;

  for (int t = 0; t < CT; t++) {
    const size_t rowb = (size_t)(t0 + t) * HDIM + hb;
    const unsigned* kw = (const unsigned*)(kb + rowb + w * 16);
    const unsigned* rw = (const unsigned*)(rb + rowb + w * 16);
    const float* tdw = td + rowb + w * 16;
    const float vi = __bfloat162float(vb[rowb + i]);
    float p = 0.f;
#pragma unroll
    for (int m = 0; m < 8; m++) {
      const unsigned kpair = kw[m];
      const unsigned rpair = rw[m];
      const float k0 = __builtin_bit_cast(float, kpair << 16);
      const float k1 = __builtin_bit_cast(float, kpair & 0xffff0000u);
      const float r0 = __builtin_bit_cast(float, rpair << 16);
      const float r1 = __builtin_bit_cast(float, rpair & 0xffff0000u);
      const float td0 = tdw[2 * m];
      const float td1 = tdw[2 * m + 1];
      const float kv0 = vi * k0;
      const float kv1 = vi * k1;
      p = fmaf(r0, s[2 * m], p);
      p = fmaf(r1, s[2 * m + 1], p);
      s[2 * m] = fmaf(s[2 * m], td0, kv0);
      s[2 * m + 1] = fmaf(s[2 * m + 1], td1, kv1);
    }
    const float rself = __bfloat162float(rb[rowb + jSelf]);
    if (i < 16) rtbase[(size_t)t * HSZ] = __float2bfloat16(rself * Aself);
    Aself *= td[rowb + jSelf];

    plds[t & 1][w][i] = p;
    __syncthreads();
    if (w == 0) {
      wkv[rowb + i] = plds[t & 1][0][i] + plds[t & 1][1][i] +
                      plds[t & 1][2][i] + plds[t & 1][3][i];
    }
  }
  if (i < 16) Ptot[((size_t)c * NHEAD + h) * HSZ + jSelf] = Aself;
  float* qbase = qT + (((size_t)c * NHEAD + h) * HSZ + w * 16) * HSZ + i;
#pragma unroll
  for (int q = 0; q < 16; q++) qbase[(size_t)q * HSZ] = s[q];
}

// ---------- sequential chunk combine: s0b (bf16) per chunk + s2out ----------
__global__ __launch_bounds__(64) void scan_s_kernel(const float* __restrict__ qT,
                                                    const float* __restrict__ Ptot,
                                                    const float* __restrict__ s2in,
                                                    __hip_bfloat16* __restrict__ s0b,
                                                    float* __restrict__ s2out) {
  const int h = blockIdx.x, i = blockIdx.y, j = threadIdx.x;
  float s = s2in[((size_t)h * HSZ + i) * HSZ + j];
#pragma unroll 4
  for (int c = 0; c < NC; c++) {
    s0b[(((size_t)c * NHEAD + h) * HSZ + i) * HSZ + j] = __float2bfloat16(s);
    s = fmaf(s, Ptot[((size_t)c * NHEAD + h) * HSZ + j],
             qT[(((size_t)c * NHEAD + h) * HSZ + j) * HSZ + i]);
  }
  s2out[((size_t)h * HSZ + i) * HSZ + j] = s;
}

// ---------- correction GEMM: wkv[c*CT+t][h][i] += sum_j rt[t][j] * s0b[i][j] ----------
__global__ __launch_bounds__(256) void corr_kernel(const __hip_bfloat16* __restrict__ rt,
                                                   const __hip_bfloat16* __restrict__ s0b,
                                                   float* __restrict__ wkv) {
  const int c = blockIdx.x, h = blockIdx.y;
  const int w = threadIdx.x >> 6;
  const int lane = threadIdx.x & 63;
  const int lr = lane & 15, lk = (lane >> 4) * 8;
  const __hip_bfloat16* rbase = rt + (((size_t)c * NHEAD + h) * CT) * HSZ;
  const __hip_bfloat16* sbase = s0b + (((size_t)c * NHEAD + h) * HSZ) * HSZ;
  float* wbase = wkv + (size_t)(c * CT) * HDIM + h * HSZ;
#pragma unroll
  for (int mt = 0; mt < CT / 16; mt++) {
    f32x4 acc = {0.f, 0.f, 0.f, 0.f};
#pragma unroll
    for (int ks = 0; ks < 2; ks++) {
      bf16x8 af = *(const bf16x8*)(rbase + (size_t)(mt * 16 + lr) * HSZ + ks * 32 + lk);
      bf16x8 bf = *(const bf16x8*)(sbase + (size_t)(w * 16 + lr) * HSZ + ks * 32 + lk);
      acc = __builtin_amdgcn_mfma_f32_16x16x32_bf16(af, bf, acc, 0, 0, 0);
    }
    const int row = mt * 16 + (lane >> 4) * 4;
    const int col = w * 16 + lr;
#pragma unroll
    for (int r = 0; r < 4; r++)
      wbase[(size_t)(row + r) * HDIM + col] += acc[r];
  }
}

// ---------- group norm over HS (+diag wkv term) + scale/bias + gate ----------
__global__ __launch_bounds__(256) void gnorm_kernel(const float* __restrict__ wkv,
                                                    const __hip_bfloat16* __restrict__ kb,
                                                    const __hip_bfloat16* __restrict__ rb,
                                                    const float* __restrict__ tf,
                                                    const __hip_bfloat16* __restrict__ vb,
                                                    const __hip_bfloat16* __restrict__ gb,
                                                    const float* __restrict__ lnw,
                                                    const float* __restrict__ lnb,
                                                    __hip_bfloat16* __restrict__ yA) {
  const int t = blockIdx.x;
  const int wid = threadIdx.x >> 6, j = threadIdx.x & 63;
  const int h = blockIdx.y * 4 + wid;
  const size_t idx = (size_t)t * HDIM + h * HSZ + j;
  const float kj = __bfloat162float(kb[idx]);
  const float rj = __bfloat162float(rb[idx]);
  const float dg = waveRedSum(rj * tf[h * HSZ + j] * kj);
  const float v = wkv[idx] + dg * __bfloat162float(vb[idx]);
  const float mu = waveRedSum(v) * (1.f / HSZ);
  const float d = v - mu;
  const float var = waveRedSum(d * d) * (1.f / HSZ);
  float y = d * rsqrtf(var + 1e-5f);
  y = y * lnw[h * HSZ + j] + lnb[h * HSZ + j];
  y *= __bfloat162float(gb[idx]);
  yA[idx] = __float2bfloat16(y);
}

extern "C" void kernel_launch(void* const* d_in, const int* in_sizes, int n_in,
                              void* d_out, int out_size, void* d_ws, size_t ws_size,
                              hipStream_t stream) {
  (void)in_sizes; (void)n_in; (void)out_size; (void)ws_size;

  const float* x    = (const float*)d_in[0];
  const float* s1   = (const float*)d_in[1];
  const float* s2   = (const float*)d_in[2];
  const float* ln1w = (const float*)d_in[3];
  const float* ln1b = (const float*)d_in[4];
  const float* tmx  = (const float*)d_in[5];
  const float* tmaa = (const float*)d_in[6];
  const float* w1   = (const float*)d_in[7];
  const float* w2   = (const float*)d_in[8];
  const float* dw1  = (const float*)d_in[9];
  const float* dw2  = (const float*)d_in[10];
  const float* dp   = (const float*)d_in[11];
  const float* tf   = (const float*)d_in[12];
  const float* Wr   = (const float*)d_in[13];
  const float* Wk   = (const float*)d_in[14];
  const float* Wv   = (const float*)d_in[15];
  const float* Wg   = (const float*)d_in[16];
  const float* Wo   = (const float*)d_in[17];
  const float* lnxw = (const float*)d_in[18];
  const float* lnxb = (const float*)d_in[19];

  float* out0  = (float*)d_out;
  float* s1out = out0 + (size_t)TLEN * HDIM;
  float* s2out = s1out + HDIM;

  char* wp = (char*)d_ws;
  size_t off = 0;
  auto carve = [&](size_t bytes) -> void* {
    void* r = wp + off;
    off += (bytes + 255) & ~(size_t)255;
    return r;
  };

  __hip_bfloat16* wrt  = (__hip_bfloat16*)carve((size_t)HDIM * HDIM * 2);
  __hip_bfloat16* wkt  = (__hip_bfloat16*)carve((size_t)HDIM * HDIM * 2);
  __hip_bfloat16* wvt  = (__hip_bfloat16*)carve((size_t)HDIM * HDIM * 2);
  __hip_bfloat16* wgt  = (__hip_bfloat16*)carve((size_t)HDIM * HDIM * 2);
  __hip_bfloat16* wot  = (__hip_bfloat16*)carve((size_t)HDIM * HDIM * 2);
  __hip_bfloat16* w1t  = (__hip_bfloat16*)carve((size_t)160 * HDIM * 2);
  __hip_bfloat16* dw1t = (__hip_bfloat16*)carve((size_t)64 * HDIM * 2);
  __hip_bfloat16* dw2t = (__hip_bfloat16*)carve((size_t)HDIM * 64 * 2);
  float* xl            = (float*)carve((size_t)THE * 4);
  __hip_bfloat16* xxx  = (__hip_bfloat16*)carve((size_t)THE * 2);
  float* t5            = (float*)carve((size_t)TLEN * 160 * 4);
  __hip_bfloat16* x5b  = (__hip_bfloat16*)carve((size_t)5 * THE * 2);
  __hip_bfloat16* rb   = (__hip_bfloat16*)carve((size_t)THE * 2);
  __hip_bfloat16* kb   = (__hip_bfloat16*)carve((size_t)THE * 2);
  __hip_bfloat16* vb   = (__hip_bfloat16*)carve((size_t)THE * 2);
  __hip_bfloat16* gb   = (__hip_bfloat16*)carve((size_t)THE * 2);
  __hip_bfloat16* tw   = (__hip_bfloat16*)carve((size_t)TLEN * 64 * 2);
  float* td            = (float*)carve((size_t)THE * 4);
  float* wkv           = (float*)carve((size_t)THE * 4);
  __hip_bfloat16* yA   = (__hip_bfloat16*)carve((size_t)THE * 2);
  (void)t5; (void)tw;

  // Aliased scratch (all regions dead at time of use) -- unchanged from r15.
  float* qT            = (float*)x5b;
  __hip_bfloat16* rt   = (__hip_bfloat16*)xl;
  __hip_bfloat16* s0b  = (__hip_bfloat16*)td;
  float* Ptot          = (float*)t5;
  float* pg1           = (float*)td;
  float* pg4           = (float*)xxx;
  float* pg6           = (float*)x5b;

  // K0: all weight transposes in one dispatch (z<5 fast, z>=5 guarded)
  {
    TrAllArgs ta{};
    const float* s8[8] = {Wr, Wk, Wv, Wg, Wo, w1, dw1, dw2};
    __hip_bfloat16* d8[8] = {wrt, wkt, wvt, wgt, wot, w1t, dw1t, dw2t};
    const int Rs[8] = {0, 0, 0, 0, 0, HDIM, HDIM, 64};
    const int Cs[8] = {0, 0, 0, 0, 0, 160, 64, HDIM};
    for (int z = 0; z < 8; z++) { ta.src[z] = s8[z]; ta.dst[z] = d8[z]; ta.R[z] = Rs[z]; ta.C[z] = Cs[z]; }
    transp_all<<<dim3(64, 64, 8), 256, 0, stream>>>(ta);
  }

  // K1: layernorm + token-shift fused -> xl, xxx
  ln1_kernel<<<dim3(TLEN), 256, 0, stream>>>(x, ln1w, ln1b, s1, tmx, xl, xxx, s1out);

  // G1: t5-partials = xxx @ w1 slices (split-K=8); combine fused into mix
  {
    GemmArgs g{};
    for (int ks = 0; ks < 8; ks++) {
      g.A[ks] = xxx + ks * 256;
      g.B[ks] = w1t + ks * 256;
      g.C[ks] = pg1 + (size_t)ks * TLEN * 160;
      g.epi[ks] = 6;
    }
    g.M = TLEN; g.N = 160; g.K = 256; g.Ks = HDIM;
    gemm_bt<<<dim3(TLEN / 128, 2, 8), 256, 0, stream>>>(g);
  }

  // K4: mix (+G1 combine) -> x5 (5 planes, bf16)
  mix_kernel<<<dim3(HDIM / 256, TLEN / 8), 256, 0, stream>>>(pg1, xl, s1, w2, tmaa, x5b);

  // G2: r, k, v, g  (batched z=4)
  {
    GemmArgs g{};
    g.A[0] = x5b + (size_t)3 * THE; g.B[0] = wrt; g.C[0] = rb; g.epi[0] = 0;
    g.A[1] = x5b + (size_t)1 * THE; g.B[1] = wkt; g.C[1] = kb; g.epi[1] = 0;
    g.A[2] = x5b + (size_t)2 * THE; g.B[2] = wvt; g.C[2] = vb; g.epi[2] = 0;
    g.A[3] = x5b + (size_t)4 * THE; g.B[3] = wgt; g.C[3] = gb; g.epi[3] = 1;
    g.M = TLEN; g.N = HDIM; g.K = HDIM; g.Ks = HDIM;
    gemm_bt<<<dim3(TLEN / 128, HDIM / 128, 4), 256, 0, stream>>>(g);
  }

  // G4: tw-partials = mw @ dw1 slices (split-K=8); combine fused into tdcalc
  {
    GemmArgs g{};
    for (int ks = 0; ks < 8; ks++) {
      g.A[ks] = x5b + ks * 256;          // plane 0 = mw
      g.B[ks] = dw1t + ks * 256;
      g.C[ks] = pg4 + (size_t)ks * TLEN * 64;
      g.epi[ks] = 6;
    }
    g.M = TLEN; g.N = 64; g.K = 256; g.Ks = HDIM;
    gemm_bt<<<dim3(TLEN / 128, 1, 8), 256, 0, stream>>>(g);
  }

  // G5': td = exp(-exp(clip(tanh(sum pg4) @ dw2 + p))) -- fused combine + dot
  tdcalc_kernel<<<dim3(TLEN / 4, HDIM / 256), 256, 0, stream>>>(pg4, dw2t, dp, td);

  // Scan stage: local pass (+decay fused), chunk combine, MFMA correction
  scan_local_kernel<<<dim3(NC * NHEAD), 256, 0, stream>>>(kb, rb, td, vb, wkv, qT, rt, Ptot);
  scan_s_kernel<<<dim3(NHEAD, HSZ), 64, 0, stream>>>(qT, Ptot, s2, s0b, s2out);
  corr_kernel<<<dim3(NC, NHEAD), 256, 0, stream>>>(rt, s0b, wkv);

  // K7: group-norm (+diag term) + gate -> yA (bf16)
  gnorm_kernel<<<dim3(TLEN, NHEAD / 4), 256, 0, stream>>>(wkv, kb, rb, tf, vb, gb, lnxw, lnxb, yA);

  // G6: out = x + yA @ W_o  -- split-K=4 (512 blocks = 2 blocks/CU TLP threshold)
  {
    GemmArgs g{};
    for (int ks = 0; ks < 4; ks++) {
      g.A[ks] = yA + ks * 512;
      g.B[ks] = wot + ks * 512;
      g.C[ks] = pg6 + (size_t)ks * THE;
      g.epi[ks] = 6;
    }
    g.M = TLEN; g.N = HDIM; g.K = 512; g.Ks = HDIM;
    gemm_bt<<<dim3(TLEN / 128, HDIM / 128, 4), 256, 0, stream>>>(g);
    comb4_resid<<<dim3(THE / 4 / 256), 256, 0, stream>>>(pg6, x, out0);
  }
}